// Round 4
// baseline (1931.582 us; speedup 1.0000x reference)
//
#include <hip/hip_runtime.h>
#include <hip/hip_bf16.h>

// Problem constants
#define NF   128   // in_channels
#define DD1  256   // dim_1
#define DD2  64    // dim_1/4
#define HATT 128   // attention hidden

static inline int cdiv(int a, int b) { return (a + b - 1) / b; }

// ---------------------------------------------------------------------------
// Pass 1: degree count + per-edge rank capture (rank < 2^16 since max deg ~45).
// ---------------------------------------------------------------------------
__global__ __launch_bounds__(256) void count_rank(const int* __restrict__ nidx,
                                                  const int* __restrict__ eidx,
                                                  int* __restrict__ deg,
                                                  int* __restrict__ rank,
                                                  int N, int E) {
    int e = blockIdx.x * 256 + threadIdx.x;
    if (e < E) {
        const int vn = nidx[e], ve = eidx[e];
        const int rn = atomicAdd(&deg[vn], 1);
        const int re = atomicAdd(&deg[N + ve], 1);
        rank[e] = rn | (re << 16);
    }
}

__global__ __launch_bounds__(256) void scan_blocks(const int* __restrict__ in,
                                                   int* __restrict__ out,
                                                   int* __restrict__ partials, int n) {
    __shared__ int s[256];
    const int base = blockIdx.x * 1024;
    const int t = threadIdx.x;
    int v[4], sum = 0;
#pragma unroll
    for (int i = 0; i < 4; i++) {
        const int idx = base + t * 4 + i;
        v[i] = (idx < n) ? in[idx] : 0;
        sum += v[i];
    }
    s[t] = sum;
    __syncthreads();
    for (int o = 1; o < 256; o <<= 1) {
        int x = 0;
        if (t >= o) x = s[t - o];
        __syncthreads();
        if (t >= o) s[t] += x;
        __syncthreads();
    }
    if (t == 255) partials[blockIdx.x] = s[255];
    int run = (t == 0) ? 0 : s[t - 1];
#pragma unroll
    for (int i = 0; i < 4; i++) {
        const int idx = base + t * 4 + i;
        if (idx < n) out[idx] = run;
        run += v[i];
    }
}

// 512 threads: handles up to 512 partials (batched path needs 391).
__global__ __launch_bounds__(512) void scan_partials(int* __restrict__ partials, int P) {
    __shared__ int s[512];
    const int t = threadIdx.x;
    s[t] = (t < P) ? partials[t] : 0;
    __syncthreads();
    for (int o = 1; o < 512; o <<= 1) {
        int x = 0;
        if (t >= o) x = s[t - o];
        __syncthreads();
        if (t >= o) s[t] += x;
        __syncthreads();
    }
    if (t < P) partials[t] = (t == 0) ? 0 : s[t - 1];
}

__global__ __launch_bounds__(256) void scan_add(int* __restrict__ off,
                                                const int* __restrict__ partials,
                                                int n, int total) {
    const int idx = blockIdx.x * 256 + threadIdx.x;
    if (idx < n) off[idx] += partials[idx >> 10];
    if (idx == 0) off[n] = total;
}

// ---------------------------------------------------------------------------
// Pass 2: store-only CSR fill, sharded by destination-vertex range.
// ---------------------------------------------------------------------------
__global__ __launch_bounds__(256) void build_fill(const int* __restrict__ nidx,
                                                  const int* __restrict__ eidx,
                                                  const int* __restrict__ rank,
                                                  const int* __restrict__ off,
                                                  int* __restrict__ srcidx,
                                                  int N, int E, int shardSize) {
    const int shard = blockIdx.x & 7;
    const int chunk = blockIdx.x >> 3;
    const int lo = shard * shardSize;
    const int hi = lo + shardSize;
    const int base = chunk * 1024;
#pragma unroll
    for (int i = 0; i < 4; i++) {
        const int e = base + i * 256 + threadIdx.x;
        if (e < E) {
            const int vn = nidx[e], ve = eidx[e];
            const int rk = rank[e];
            if (vn >= lo && vn < hi)
                srcidx[off[vn] + (rk & 0xffff)] = ve;
            if (ve >= lo && ve < hi)
                srcidx[off[N + ve] + (rk >> 16)] = vn;
        }
    }
}

__global__ __launch_bounds__(256) void invert_deg_int(const int* __restrict__ deg,
                                                      float* __restrict__ inv, int n) {
    int t = blockIdx.x * 256 + threadIdx.x;
    if (t < n) {
        const int v = deg[t];
        inv[t] = (v > 0) ? 1.0f / (float)v : 0.f;
    }
}

// ===========================================================================
// Batched (4-graph) CSR build. One scan over the concatenated degree arrays
// gives GLOBAL offsets into a single srcidx[8E].
// ===========================================================================
struct BuildB {
    const int* nidx[4];
    const int* eidx[4];
    int* deg;        // [4 * 2N]  (transient, aliased into RA)
    int* rank;       // [4 * E]   (transient, aliased into RA)
    const int* off;  // [4 * 2N + 1] global offsets
    int* srcidx;     // [4 * 2E]
    int Nn, E, shardSize;
};

__global__ __launch_bounds__(256) void count_rank_b(BuildB a) {
    const int g = blockIdx.y;
    const int e = blockIdx.x * 256 + threadIdx.x;
    if (e < a.E) {
        const int vn = a.nidx[g][e], ve = a.eidx[g][e];
        int* dg = a.deg + (size_t)g * 2 * a.Nn;
        const int rn = atomicAdd(&dg[vn], 1);
        const int re = atomicAdd(&dg[a.Nn + ve], 1);
        a.rank[(size_t)g * a.E + e] = rn | (re << 16);
    }
}

__global__ __launch_bounds__(256) void build_fill_b(BuildB a) {
    const int g = blockIdx.y;
    const int shard = blockIdx.x & 7;
    const int chunk = blockIdx.x >> 3;
    const int lo = shard * a.shardSize;
    const int hi = lo + a.shardSize;
    const int base = chunk * 1024;
    const int* __restrict__ nidx = a.nidx[g];
    const int* __restrict__ eidx = a.eidx[g];
    const int* __restrict__ rank = a.rank + (size_t)g * a.E;
    const int* __restrict__ off  = a.off + (size_t)g * 2 * a.Nn;
#pragma unroll
    for (int i = 0; i < 4; i++) {
        const int e = base + i * 256 + threadIdx.x;
        if (e < a.E) {
            const int vn = nidx[e], ve = eidx[e];
            const int rk = rank[e];
            if (vn >= lo && vn < hi)
                a.srcidx[off[vn] + (rk & 0xffff)] = ve;
            if (ve >= lo && ve < hi)
                a.srcidx[off[a.Nn + ve] + (rk >> 16)] = vn;
        }
    }
}

// ---------------------------------------------------------------------------
// CSR gather, D=128 (per-graph, fallback path).
// ---------------------------------------------------------------------------
__global__ __launch_bounds__(256) void gather_rows_128(const float* __restrict__ src,
                                                       const int* __restrict__ off,
                                                       const int* __restrict__ srcidx,
                                                       const float* __restrict__ scale,
                                                       float* __restrict__ dst, int Nn) {
    const int row = blockIdx.x * 16 + (threadIdx.x >> 4);
    if (row >= Nn) return;
    const int c = (threadIdx.x & 15) << 2;
    const int j0 = off[row], j1 = off[row + 1];
    float4 pa = make_float4(0.f, 0.f, 0.f, 0.f);
    float4 pb = make_float4(0.f, 0.f, 0.f, 0.f);
    float4 qa = make_float4(0.f, 0.f, 0.f, 0.f);
    float4 qb = make_float4(0.f, 0.f, 0.f, 0.f);
    int j = j0;
    for (; j + 3 < j1; j += 4) {
        const int s0 = srcidx[j + 0];
        const int s1 = srcidx[j + 1];
        const int s2 = srcidx[j + 2];
        const int s3 = srcidx[j + 3];
        const float4 v0a = *(const float4*)&src[(size_t)s0 * 128 + c];
        const float4 v0b = *(const float4*)&src[(size_t)s0 * 128 + c + 64];
        const float4 v1a = *(const float4*)&src[(size_t)s1 * 128 + c];
        const float4 v1b = *(const float4*)&src[(size_t)s1 * 128 + c + 64];
        const float4 v2a = *(const float4*)&src[(size_t)s2 * 128 + c];
        const float4 v2b = *(const float4*)&src[(size_t)s2 * 128 + c + 64];
        const float4 v3a = *(const float4*)&src[(size_t)s3 * 128 + c];
        const float4 v3b = *(const float4*)&src[(size_t)s3 * 128 + c + 64];
        pa.x += v0a.x + v1a.x; pa.y += v0a.y + v1a.y;
        pa.z += v0a.z + v1a.z; pa.w += v0a.w + v1a.w;
        qa.x += v2a.x + v3a.x; qa.y += v2a.y + v3a.y;
        qa.z += v2a.z + v3a.z; qa.w += v2a.w + v3a.w;
        pb.x += v0b.x + v1b.x; pb.y += v0b.y + v1b.y;
        pb.z += v0b.z + v1b.z; pb.w += v0b.w + v1b.w;
        qb.x += v2b.x + v3b.x; qb.y += v2b.y + v3b.y;
        qb.z += v2b.z + v3b.z; qb.w += v2b.w + v3b.w;
    }
    for (; j < j1; j++) {
        const int s0 = srcidx[j];
        const float4 va = *(const float4*)&src[(size_t)s0 * 128 + c];
        const float4 vb = *(const float4*)&src[(size_t)s0 * 128 + c + 64];
        pa.x += va.x; pa.y += va.y; pa.z += va.z; pa.w += va.w;
        pb.x += vb.x; pb.y += vb.y; pb.z += vb.z; pb.w += vb.w;
    }
    float4 aca = make_float4(pa.x + qa.x, pa.y + qa.y, pa.z + qa.z, pa.w + qa.w);
    float4 acb = make_float4(pb.x + qb.x, pb.y + qb.y, pb.z + qb.z, pb.w + qb.w);
    if (scale) {
        const float s = scale[row];
        aca.x *= s; aca.y *= s; aca.z *= s; aca.w *= s;
        acb.x *= s; acb.y *= s; acb.z *= s; acb.w *= s;
    }
    *(float4*)&dst[(size_t)row * 128 + c] = aca;
    *(float4*)&dst[(size_t)row * 128 + c + 64] = acb;
}

// Half-batched variant: TWO graphs per launch so the ping buffer is [2N,128].
struct Gather128H {
    const float* src[2];       // per-graph source base (local rows)
    float* dst;                // contiguous [2*Nn][128] from dst
    const int* off;            // global off [8N+1]
    const int* srcidx;
    const float* dinv;         // global [8N] or nullptr
    int gbase;                 // 0 or 2
    int passBase;              // 0 = node CSR, Nn = edge CSR
    int Nn;
};

__global__ __launch_bounds__(256) void gather128_h(Gather128H a) {
    const int gr = blockIdx.x * 16 + (threadIdx.x >> 4);
    if (gr >= 2 * a.Nn) return;
    const int gl = gr / a.Nn;              // 0/1 within this half
    const int row = gr - gl * a.Nn;
    const float* __restrict__ src = a.src[gl];
    const int ob = (a.gbase + gl) * 2 * a.Nn + a.passBase + row;
    const int c = (threadIdx.x & 15) << 2;
    const int j0 = a.off[ob], j1 = a.off[ob + 1];
    float4 pa = make_float4(0.f, 0.f, 0.f, 0.f);
    float4 pb = make_float4(0.f, 0.f, 0.f, 0.f);
    float4 qa = make_float4(0.f, 0.f, 0.f, 0.f);
    float4 qb = make_float4(0.f, 0.f, 0.f, 0.f);
    int j = j0;
    for (; j + 3 < j1; j += 4) {
        const int s0 = a.srcidx[j + 0];
        const int s1 = a.srcidx[j + 1];
        const int s2 = a.srcidx[j + 2];
        const int s3 = a.srcidx[j + 3];
        const float4 v0a = *(const float4*)&src[(size_t)s0 * 128 + c];
        const float4 v0b = *(const float4*)&src[(size_t)s0 * 128 + c + 64];
        const float4 v1a = *(const float4*)&src[(size_t)s1 * 128 + c];
        const float4 v1b = *(const float4*)&src[(size_t)s1 * 128 + c + 64];
        const float4 v2a = *(const float4*)&src[(size_t)s2 * 128 + c];
        const float4 v2b = *(const float4*)&src[(size_t)s2 * 128 + c + 64];
        const float4 v3a = *(const float4*)&src[(size_t)s3 * 128 + c];
        const float4 v3b = *(const float4*)&src[(size_t)s3 * 128 + c + 64];
        pa.x += v0a.x + v1a.x; pa.y += v0a.y + v1a.y;
        pa.z += v0a.z + v1a.z; pa.w += v0a.w + v1a.w;
        qa.x += v2a.x + v3a.x; qa.y += v2a.y + v3a.y;
        qa.z += v2a.z + v3a.z; qa.w += v2a.w + v3a.w;
        pb.x += v0b.x + v1b.x; pb.y += v0b.y + v1b.y;
        pb.z += v0b.z + v1b.z; pb.w += v0b.w + v1b.w;
        qb.x += v2b.x + v3b.x; qb.y += v2b.y + v3b.y;
        qb.z += v2b.z + v3b.z; qb.w += v2b.w + v3b.w;
    }
    for (; j < j1; j++) {
        const int s0 = a.srcidx[j];
        const float4 va = *(const float4*)&src[(size_t)s0 * 128 + c];
        const float4 vb = *(const float4*)&src[(size_t)s0 * 128 + c + 64];
        pa.x += va.x; pa.y += va.y; pa.z += va.z; pa.w += va.w;
        pb.x += vb.x; pb.y += vb.y; pb.z += vb.z; pb.w += vb.w;
    }
    float4 aca = make_float4(pa.x + qa.x, pa.y + qa.y, pa.z + qa.z, pa.w + qa.w);
    float4 acb = make_float4(pb.x + qb.x, pb.y + qb.y, pb.z + qb.z, pb.w + qb.w);
    if (a.dinv) {
        const float s = a.dinv[ob];
        aca.x *= s; aca.y *= s; aca.z *= s; aca.w *= s;
        acb.x *= s; acb.y *= s; acb.z *= s; acb.w *= s;
    }
    *(float4*)&a.dst[(size_t)gr * 128 + c] = aca;
    *(float4*)&a.dst[(size_t)gr * 128 + c + 64] = acb;
}

// ---------------------------------------------------------------------------
// CSR gather, D=64 (per-graph fallback).
// ---------------------------------------------------------------------------
__global__ __launch_bounds__(256) void gather_rows_64(const float* __restrict__ src,
                                                      const int* __restrict__ off,
                                                      const int* __restrict__ srcidx,
                                                      const float* __restrict__ scale,
                                                      const float* __restrict__ post_bias,
                                                      float* __restrict__ dst, int Nn) {
    const int row = blockIdx.x * 32 + (threadIdx.x >> 3);
    if (row >= Nn) return;
    const int c = (threadIdx.x & 7) << 2;
    const int j0 = off[row], j1 = off[row + 1];
    float4 pa = make_float4(0.f, 0.f, 0.f, 0.f);
    float4 pb = make_float4(0.f, 0.f, 0.f, 0.f);
    float4 qa = make_float4(0.f, 0.f, 0.f, 0.f);
    float4 qb = make_float4(0.f, 0.f, 0.f, 0.f);
    int j = j0;
    for (; j + 3 < j1; j += 4) {
        const int s0 = srcidx[j + 0];
        const int s1 = srcidx[j + 1];
        const int s2 = srcidx[j + 2];
        const int s3 = srcidx[j + 3];
        const float4 v0a = *(const float4*)&src[(size_t)s0 * 64 + c];
        const float4 v0b = *(const float4*)&src[(size_t)s0 * 64 + c + 32];
        const float4 v1a = *(const float4*)&src[(size_t)s1 * 64 + c];
        const float4 v1b = *(const float4*)&src[(size_t)s1 * 64 + c + 32];
        const float4 v2a = *(const float4*)&src[(size_t)s2 * 64 + c];
        const float4 v2b = *(const float4*)&src[(size_t)s2 * 64 + c + 32];
        const float4 v3a = *(const float4*)&src[(size_t)s3 * 64 + c];
        const float4 v3b = *(const float4*)&src[(size_t)s3 * 64 + c + 32];
        pa.x += v0a.x + v1a.x; pa.y += v0a.y + v1a.y;
        pa.z += v0a.z + v1a.z; pa.w += v0a.w + v1a.w;
        qa.x += v2a.x + v3a.x; qa.y += v2a.y + v3a.y;
        qa.z += v2a.z + v3a.z; qa.w += v2a.w + v3a.w;
        pb.x += v0b.x + v1b.x; pb.y += v0b.y + v1b.y;
        pb.z += v0b.z + v1b.z; pb.w += v0b.w + v1b.w;
        qb.x += v2b.x + v3b.x; qb.y += v2b.y + v3b.y;
        qb.z += v2b.z + v3b.z; qb.w += v2b.w + v3b.w;
    }
    for (; j < j1; j++) {
        const int s0 = srcidx[j];
        const float4 va = *(const float4*)&src[(size_t)s0 * 64 + c];
        const float4 vb = *(const float4*)&src[(size_t)s0 * 64 + c + 32];
        pa.x += va.x; pa.y += va.y; pa.z += va.z; pa.w += va.w;
        pb.x += vb.x; pb.y += vb.y; pb.z += vb.z; pb.w += vb.w;
    }
    float4 aca = make_float4(pa.x + qa.x, pa.y + qa.y, pa.z + qa.z, pa.w + qa.w);
    float4 acb = make_float4(pb.x + qb.x, pb.y + qb.y, pb.z + qb.z, pb.w + qb.w);
    if (scale) {
        const float s = scale[row];
        aca.x *= s; aca.y *= s; aca.z *= s; aca.w *= s;
        acb.x *= s; acb.y *= s; acb.z *= s; acb.w *= s;
    }
    if (post_bias) {
        aca.x = fmaxf(aca.x + post_bias[c + 0], 0.f);
        aca.y = fmaxf(aca.y + post_bias[c + 1], 0.f);
        aca.z = fmaxf(aca.z + post_bias[c + 2], 0.f);
        aca.w = fmaxf(aca.w + post_bias[c + 3], 0.f);
        acb.x = fmaxf(acb.x + post_bias[c + 32], 0.f);
        acb.y = fmaxf(acb.y + post_bias[c + 33], 0.f);
        acb.z = fmaxf(acb.z + post_bias[c + 34], 0.f);
        acb.w = fmaxf(acb.w + post_bias[c + 35], 0.f);
    }
    *(float4*)&dst[(size_t)row * 64 + c] = aca;
    *(float4*)&dst[(size_t)row * 64 + c + 32] = acb;
}

struct Gather64B {
    const float* src[4];
    float* dst;                // contiguous [4*Nn][64]
    const int* off;
    const int* srcidx;
    const float* dinv;         // global [8N] or nullptr
    const float* post_bias;    // nullptr or b2 (fused relu)
    int passBase;
    int Nn;
};

__global__ __launch_bounds__(256) void gather64_b(Gather64B a) {
    const int gr = blockIdx.x * 32 + (threadIdx.x >> 3);
    if (gr >= 4 * a.Nn) return;
    const int g = gr / a.Nn;
    const int row = gr - g * a.Nn;
    const float* __restrict__ src = a.src[g];
    const int ob = g * 2 * a.Nn + a.passBase + row;
    const int c = (threadIdx.x & 7) << 2;
    const int j0 = a.off[ob], j1 = a.off[ob + 1];
    float4 pa = make_float4(0.f, 0.f, 0.f, 0.f);
    float4 pb = make_float4(0.f, 0.f, 0.f, 0.f);
    float4 qa = make_float4(0.f, 0.f, 0.f, 0.f);
    float4 qb = make_float4(0.f, 0.f, 0.f, 0.f);
    int j = j0;
    for (; j + 3 < j1; j += 4) {
        const int s0 = a.srcidx[j + 0];
        const int s1 = a.srcidx[j + 1];
        const int s2 = a.srcidx[j + 2];
        const int s3 = a.srcidx[j + 3];
        const float4 v0a = *(const float4*)&src[(size_t)s0 * 64 + c];
        const float4 v0b = *(const float4*)&src[(size_t)s0 * 64 + c + 32];
        const float4 v1a = *(const float4*)&src[(size_t)s1 * 64 + c];
        const float4 v1b = *(const float4*)&src[(size_t)s1 * 64 + c + 32];
        const float4 v2a = *(const float4*)&src[(size_t)s2 * 64 + c];
        const float4 v2b = *(const float4*)&src[(size_t)s2 * 64 + c + 32];
        const float4 v3a = *(const float4*)&src[(size_t)s3 * 64 + c];
        const float4 v3b = *(const float4*)&src[(size_t)s3 * 64 + c + 32];
        pa.x += v0a.x + v1a.x; pa.y += v0a.y + v1a.y;
        pa.z += v0a.z + v1a.z; pa.w += v0a.w + v1a.w;
        qa.x += v2a.x + v3a.x; qa.y += v2a.y + v3a.y;
        qa.z += v2a.z + v3a.z; qa.w += v2a.w + v3a.w;
        pb.x += v0b.x + v1b.x; pb.y += v0b.y + v1b.y;
        pb.z += v0b.z + v1b.z; pb.w += v0b.w + v1b.w;
        qb.x += v2b.x + v3b.x; qb.y += v2b.y + v3b.y;
        qb.z += v2b.z + v3b.z; qb.w += v2b.w + v3b.w;
    }
    for (; j < j1; j++) {
        const int s0 = a.srcidx[j];
        const float4 va = *(const float4*)&src[(size_t)s0 * 64 + c];
        const float4 vb = *(const float4*)&src[(size_t)s0 * 64 + c + 32];
        pa.x += va.x; pa.y += va.y; pa.z += va.z; pa.w += va.w;
        pb.x += vb.x; pb.y += vb.y; pb.z += vb.z; pb.w += vb.w;
    }
    float4 aca = make_float4(pa.x + qa.x, pa.y + qa.y, pa.z + qa.z, pa.w + qa.w);
    float4 acb = make_float4(pb.x + qb.x, pb.y + qb.y, pb.z + qb.z, pb.w + qb.w);
    if (a.dinv) {
        const float s = a.dinv[ob];
        aca.x *= s; aca.y *= s; aca.z *= s; aca.w *= s;
        acb.x *= s; acb.y *= s; acb.z *= s; acb.w *= s;
    }
    if (a.post_bias) {
        aca.x = fmaxf(aca.x + a.post_bias[c + 0], 0.f);
        aca.y = fmaxf(aca.y + a.post_bias[c + 1], 0.f);
        aca.z = fmaxf(aca.z + a.post_bias[c + 2], 0.f);
        aca.w = fmaxf(aca.w + a.post_bias[c + 3], 0.f);
        acb.x = fmaxf(acb.x + a.post_bias[c + 32], 0.f);
        acb.y = fmaxf(acb.y + a.post_bias[c + 33], 0.f);
        acb.z = fmaxf(acb.z + a.post_bias[c + 34], 0.f);
        acb.w = fmaxf(acb.w + a.post_bias[c + 35], 0.f);
    }
    *(float4*)&a.dst[(size_t)gr * 64 + c] = aca;
    *(float4*)&a.dst[(size_t)gr * 64 + c + 32] = acb;
}

// ---------------------------------------------------------------------------
// GEMM1 (fallback): C[M,256] = relu(dinv[row] * (A[M,128] @ B[128,256]) + bias)
// ---------------------------------------------------------------------------
__global__ __launch_bounds__(256) void gemm1_f32(const float* __restrict__ A,
                                                 const float* __restrict__ B,
                                                 float* __restrict__ C, int M,
                                                 const float* __restrict__ dinv,
                                                 const float* __restrict__ bias) {
    __shared__ float As[32][132];   // [k][m]
    __shared__ float Bs[32][128];   // [k][n]
    const int tid = threadIdx.x;
    const int m0 = blockIdx.y * 128;
    const int bn = blockIdx.x * 128;
    const int rq = (tid >> 4) << 2;
    const int cq = (tid & 15) << 2;

    float acc[8][8] = {{0.f}};

    for (int k0 = 0; k0 < 128; k0 += 32) {
#pragma unroll
        for (int i = 0; i < 4; i++) {
            const int f = tid + 256 * i;
            const int r = f >> 3;
            const int q = (f & 7) << 2;
            const int grow = m0 + r;
            float4 v = make_float4(0.f, 0.f, 0.f, 0.f);
            if (grow < M) v = *(const float4*)&A[(size_t)grow * 128 + k0 + q];
            As[q + 0][r] = v.x;
            As[q + 1][r] = v.y;
            As[q + 2][r] = v.z;
            As[q + 3][r] = v.w;
        }
#pragma unroll
        for (int i = 0; i < 4; i++) {
            const int f = tid + 256 * i;
            const int r = f >> 5;
            const int c4 = (f & 31) << 2;
            *(float4*)&Bs[r][c4] = *(const float4*)&B[(size_t)(k0 + r) * 256 + bn + c4];
        }
        __syncthreads();
#pragma unroll
        for (int k = 0; k < 32; k++) {
            float av[8], bv[8];
            *(float4*)&av[0] = *(const float4*)&As[k][rq];
            *(float4*)&av[4] = *(const float4*)&As[k][rq + 64];
            *(float4*)&bv[0] = *(const float4*)&Bs[k][cq];
            *(float4*)&bv[4] = *(const float4*)&Bs[k][cq + 64];
#pragma unroll
            for (int r = 0; r < 8; r++)
#pragma unroll
                for (int c = 0; c < 8; c++)
                    acc[r][c] = fmaf(av[r], bv[c], acc[r][c]);
        }
        __syncthreads();
    }
#pragma unroll
    for (int r = 0; r < 8; r++) {
        const int grow = m0 + rq + (r & 3) + ((r >> 2) << 6);
        if (grow < M) {
            const float s = dinv[grow];
            float o[8];
#pragma unroll
            for (int c = 0; c < 4; c++)
                o[c] = fmaxf(fmaf(acc[r][c], s, bias[bn + cq + c]), 0.f);
#pragma unroll
            for (int c = 4; c < 8; c++)
                o[c] = fmaxf(fmaf(acc[r][c], s, bias[bn + 64 + cq + (c - 4)]), 0.f);
            *(float4*)&C[(size_t)grow * 256 + bn + cq] = *(float4*)&o[0];
            *(float4*)&C[(size_t)grow * 256 + bn + 64 + cq] = *(float4*)&o[4];
        }
    }
}

// ---------------------------------------------------------------------------
// GEMM2 (fallback): C[M,64] = A[M,256] @ B[256,64]
// ---------------------------------------------------------------------------
__global__ __launch_bounds__(256) void gemm2_f32(const float* __restrict__ A,
                                                 const float* __restrict__ B,
                                                 float* __restrict__ C, int M) {
    __shared__ float As[32][132];
    __shared__ float Bs[32][64];
    const int tid = threadIdx.x;
    const int m0 = blockIdx.y * 128;
    const int tr = (tid >> 3) << 2;
    const int tc = (tid & 7) << 3;

    float acc[4][8] = {{0.f}};

    for (int k0 = 0; k0 < 256; k0 += 32) {
#pragma unroll
        for (int i = 0; i < 4; i++) {
            const int f = tid + 256 * i;
            const int r = f >> 3;
            const int q = (f & 7) << 2;
            const int grow = m0 + r;
            float4 v = make_float4(0.f, 0.f, 0.f, 0.f);
            if (grow < M) v = *(const float4*)&A[(size_t)grow * 256 + k0 + q];
            As[q + 0][r] = v.x;
            As[q + 1][r] = v.y;
            As[q + 2][r] = v.z;
            As[q + 3][r] = v.w;
        }
#pragma unroll
        for (int i = 0; i < 2; i++) {
            const int f = tid + 256 * i;
            const int r = f >> 4;
            const int c4 = (f & 15) << 2;
            *(float4*)&Bs[r][c4] = *(const float4*)&B[(size_t)(k0 + r) * 64 + c4];
        }
        __syncthreads();
#pragma unroll
        for (int k = 0; k < 32; k++) {
            float av[4], bv[8];
            *(float4*)&av[0] = *(const float4*)&As[k][tr];
            *(float4*)&bv[0] = *(const float4*)&Bs[k][tc];
            *(float4*)&bv[4] = *(const float4*)&Bs[k][tc + 4];
#pragma unroll
            for (int r = 0; r < 4; r++)
#pragma unroll
                for (int c = 0; c < 8; c++)
                    acc[r][c] = fmaf(av[r], bv[c], acc[r][c]);
        }
        __syncthreads();
    }
#pragma unroll
    for (int r = 0; r < 4; r++) {
        const int grow = m0 + tr + r;
        if (grow < M) {
            *(float4*)&C[(size_t)grow * 64 + tc] =
                make_float4(acc[r][0], acc[r][1], acc[r][2], acc[r][3]);
            *(float4*)&C[(size_t)grow * 64 + tc + 4] =
                make_float4(acc[r][4], acc[r][5], acc[r][6], acc[r][7]);
        }
    }
}

// ===========================================================================
// Fused GEMM1+GEMM2 (batched) v3: D[M4,64] = relu(dinv*A@W1 + b1) @ W2.
// 64-row tile, acc[8][8] (LDS-balanced phase 1). Phase 2: full-tile
// Ts[128k][64m] per k-half with quad-XOR swizzle (write 4-way instead of
// 16-way; read = aligned conflict-free b128), W2 staged from L2 in 64-k
// chunks, 2-way wave-aligned k-split + one LDS reduce round.
// LDS 50KB -> 3 blocks/CU; all 256 threads active in every phase.
// ===========================================================================
struct Gemm12B {
    const float* A;      // [M4,128]
    const float* W1;     // [128,256]
    const float* W2;     // [256,64]
    const float* b1;     // [256]
    const float* dinv;   // [8N] global; d_inv at g*2N + lr
    float* D;            // [M4,64]
    int Nn;
};

__global__ __launch_bounds__(256, 3) void gemm12_b(Gemm12B a) {
    // LDS (floats):
    //  phase1: As[32][68] @ 0..2175, Bs[32][256] @ 2176..10367
    //  phase2: Ts[128][68] @ 0..8703 (swizzled), W2s[64][64] @ 8704..12799
    //  reduce: Rs[64][68] aliases Ts
    __shared__ float smem[12800];
    float* As  = smem;
    float* Bs  = smem + 2176;
    float* Ts  = smem;
    float* W2s = smem + 8704;
    float* Rs  = smem;

    const int M4 = 4 * a.Nn;
    const int tid = threadIdx.x;
    const int m0 = blockIdx.x * 64;
    const int rq = (tid >> 5) << 3;      // 8 consecutive rows per thread
    const int cq = (tid & 31) << 2;      // cols cq (half 0) and cq+128 (half 1)

    float acc[8][8] = {{0.f}};

    // ---------------- phase 1: T' = A @ W1 (64x256 per block) ----------------
    for (int k0 = 0; k0 < 128; k0 += 32) {
#pragma unroll
        for (int i = 0; i < 2; i++) {    // stage A [64 rows][32 k] -> As[k][m]
            const int f = tid + 256 * i;
            const int r = f >> 3;              // 0..63
            const int q = (f & 7) << 2;        // 0..28
            const int grow = m0 + r;
            float4 v = make_float4(0.f, 0.f, 0.f, 0.f);
            if (grow < M4) v = *(const float4*)&a.A[(size_t)grow * 128 + k0 + q];
            As[(q + 0) * 68 + r] = v.x;
            As[(q + 1) * 68 + r] = v.y;
            As[(q + 2) * 68 + r] = v.z;
            As[(q + 3) * 68 + r] = v.w;
        }
#pragma unroll
        for (int i = 0; i < 8; i++) {    // stage W1 [32 k][256]
            const int f = tid + 256 * i;
            const int r = f >> 6;
            const int c4 = (f & 63) << 2;
            *(float4*)&Bs[r * 256 + c4] = *(const float4*)&a.W1[(size_t)(k0 + r) * 256 + c4];
        }
        __syncthreads();
#pragma unroll
        for (int k = 0; k < 32; k++) {
            float av[8], bv[8];
            *(float4*)&av[0] = *(const float4*)&As[k * 68 + rq];
            *(float4*)&av[4] = *(const float4*)&As[k * 68 + rq + 4];
            *(float4*)&bv[0] = *(const float4*)&Bs[k * 256 + cq];
            *(float4*)&bv[4] = *(const float4*)&Bs[k * 256 + cq + 128];
#pragma unroll
            for (int r = 0; r < 8; r++)
#pragma unroll
                for (int c = 0; c < 8; c++)
                    acc[r][c] = fmaf(av[r], bv[c], acc[r][c]);
        }
        __syncthreads();
    }

    // per-thread epilogue constants
    float b1lo[4], b1hi[4], sc[8];
#pragma unroll
    for (int j = 0; j < 4; j++) {
        b1lo[j] = a.b1[cq + j];
        b1hi[j] = a.b1[cq + 128 + j];
    }
#pragma unroll
    for (int r = 0; r < 8; r++) {
        const int grow = m0 + rq + r;
        float sv = 0.f;
        if (grow < M4) {
            const int g = grow / a.Nn;
            const int lr = grow - g * a.Nn;
            sv = a.dinv[(size_t)g * 2 * a.Nn + lr];
        }
        sc[r] = sv;
    }

    // ---------------- phase 2: D = relu(T) @ W2 ----------------
    const int col8 = (tid & 7) << 3;          // 8 col-groups x 8 = 64 cols
    const int row4 = ((tid >> 3) & 15) << 2;  // 16 row-groups x 4 = 64 rows
    const int kpar = tid >> 7;                // 0/1 (wave-pair aligned)
    const int qi   = row4 >> 2;               // 0..15

    float4 dl[4], dh[4];
#pragma unroll
    for (int r = 0; r < 4; r++) {
        dl[r] = make_float4(0.f, 0.f, 0.f, 0.f);
        dh[r] = make_float4(0.f, 0.f, 0.f, 0.f);
    }

    for (int kh = 0; kh < 2; kh++) {
        __syncthreads();   // phase-1 / previous-half Ts+W2s reads complete
        {   // write Ts for this k-half; swizzle: phys quad = (m>>2) ^ ((k>>2)&7)
            const int x   = (tid & 31) & 7;
            const int t2  = (tid >> 5) << 1;
            const int sw0 = (t2 ^ x) << 2;
            const int sw1 = ((t2 + 1) ^ x) << 2;
#pragma unroll
            for (int j = 0; j < 4; j++) {
                float* tk = &Ts[(cq + j) * 68];
#pragma unroll
                for (int r = 0; r < 8; r++) {
                    const float v = fmaxf(fmaf(acc[r][(kh ? 4 : 0) + j], sc[r],
                                               kh ? b1hi[j] : b1lo[j]), 0.f);
                    tk[(r < 4 ? sw0 : sw1) + (r & 3)] = v;
                }
            }
        }
        for (int kc = 0; kc < 2; kc++) {
            if (kc) __syncthreads();          // chunk-0 W2s reads done
#pragma unroll
            for (int i = 0; i < 4; i++) {     // stage W2 [64 k][64] from L2
                const int f = tid + 256 * i;
                const int kr = f >> 4;
                const int c4 = (f & 15) << 2;
                *(float4*)&W2s[kr * 64 + c4] =
                    *(const float4*)&a.W2[(size_t)(kh * 128 + kc * 64 + kr) * 64 + c4];
            }
            __syncthreads();                  // Ts (kc==0) + W2s visible
#pragma unroll
            for (int jj = 0; jj < 32; jj++) {
                const int kl = (jj << 1) | kpar;                 // 0..63 in chunk
                const int sw = (qi ^ ((kl >> 2) & 7)) << 2;
                const float4 tv  = *(const float4*)&Ts[(kc * 64 + kl) * 68 + sw];
                const float4 wv0 = *(const float4*)&W2s[kl * 64 + col8];
                const float4 wv1 = *(const float4*)&W2s[kl * 64 + col8 + 4];
                dl[0].x = fmaf(tv.x, wv0.x, dl[0].x); dl[0].y = fmaf(tv.x, wv0.y, dl[0].y);
                dl[0].z = fmaf(tv.x, wv0.z, dl[0].z); dl[0].w = fmaf(tv.x, wv0.w, dl[0].w);
                dh[0].x = fmaf(tv.x, wv1.x, dh[0].x); dh[0].y = fmaf(tv.x, wv1.y, dh[0].y);
                dh[0].z = fmaf(tv.x, wv1.z, dh[0].z); dh[0].w = fmaf(tv.x, wv1.w, dh[0].w);
                dl[1].x = fmaf(tv.y, wv0.x, dl[1].x); dl[1].y = fmaf(tv.y, wv0.y, dl[1].y);
                dl[1].z = fmaf(tv.y, wv0.z, dl[1].z); dl[1].w = fmaf(tv.y, wv0.w, dl[1].w);
                dh[1].x = fmaf(tv.y, wv1.x, dh[1].x); dh[1].y = fmaf(tv.y, wv1.y, dh[1].y);
                dh[1].z = fmaf(tv.y, wv1.z, dh[1].z); dh[1].w = fmaf(tv.y, wv1.w, dh[1].w);
                dl[2].x = fmaf(tv.z, wv0.x, dl[2].x); dl[2].y = fmaf(tv.z, wv0.y, dl[2].y);
                dl[2].z = fmaf(tv.z, wv0.z, dl[2].z); dl[2].w = fmaf(tv.z, wv0.w, dl[2].w);
                dh[2].x = fmaf(tv.z, wv1.x, dh[2].x); dh[2].y = fmaf(tv.z, wv1.y, dh[2].y);
                dh[2].z = fmaf(tv.z, wv1.z, dh[2].z); dh[2].w = fmaf(tv.z, wv1.w, dh[2].w);
                dl[3].x = fmaf(tv.w, wv0.x, dl[3].x); dl[3].y = fmaf(tv.w, wv0.y, dl[3].y);
                dl[3].z = fmaf(tv.w, wv0.z, dl[3].z); dl[3].w = fmaf(tv.w, wv0.w, dl[3].w);
                dh[3].x = fmaf(tv.w, wv1.x, dh[3].x); dh[3].y = fmaf(tv.w, wv1.y, dh[3].y);
                dh[3].z = fmaf(tv.w, wv1.z, dh[3].z); dh[3].w = fmaf(tv.w, wv1.w, dh[3].w);
            }
        }
    }

    // ---------------- reduce the 2 k-parity partials, store ----------------
    __syncthreads();                          // all Ts reads done -> Rs may alias
    if (kpar == 1) {
#pragma unroll
        for (int r = 0; r < 4; r++) {
            *(float4*)&Rs[(row4 + r) * 68 + col8]     = dl[r];
            *(float4*)&Rs[(row4 + r) * 68 + col8 + 4] = dh[r];
        }
    }
    __syncthreads();
    if (kpar == 0) {
#pragma unroll
        for (int r = 0; r < 4; r++) {
            const int grow = m0 + row4 + r;
            if (grow < M4) {
                const float4 pl = *(const float4*)&Rs[(row4 + r) * 68 + col8];
                const float4 ph = *(const float4*)&Rs[(row4 + r) * 68 + col8 + 4];
                float4 ol = make_float4(dl[r].x + pl.x, dl[r].y + pl.y,
                                        dl[r].z + pl.z, dl[r].w + pl.w);
                float4 oh = make_float4(dh[r].x + ph.x, dh[r].y + ph.y,
                                        dh[r].z + ph.z, dh[r].w + ph.w);
                *(float4*)&a.D[(size_t)grow * 64 + col8]     = ol;
                *(float4*)&a.D[(size_t)grow * 64 + col8 + 4] = oh;
            }
        }
    }
}

// ---------------------------------------------------------------------------
// hyperedge embedding
// ---------------------------------------------------------------------------
__global__ __launch_bounds__(256) void hye_emb_kernel(const float* __restrict__ emb,
                                                      const int* __restrict__ hnode,
                                                      const float* __restrict__ hlen,
                                                      float* __restrict__ out, int Nn) {
    const int r = blockIdx.x * 16 + (threadIdx.x >> 4);
    const int c = (threadIdx.x & 15) << 2;
    if (r >= Nn) return;
    const int4* hp4 = (const int4*)&hnode[(size_t)r * 16];
    const int4 w0 = hp4[0], w1 = hp4[1], w2 = hp4[2], w3 = hp4[3];
    int idx[16] = {w0.x, w0.y, w0.z, w0.w, w1.x, w1.y, w1.z, w1.w,
                   w2.x, w2.y, w2.z, w2.w, w3.x, w3.y, w3.z, w3.w};
    float4 a0 = make_float4(0.f, 0.f, 0.f, 0.f);
    float4 a1 = make_float4(0.f, 0.f, 0.f, 0.f);
    float4 a2 = make_float4(0.f, 0.f, 0.f, 0.f);
    float4 a3 = make_float4(0.f, 0.f, 0.f, 0.f);
#pragma unroll
    for (int l = 0; l < 16; l += 4) {
        if (idx[l + 0] > 0) {
            const float4 v = *(const float4*)&emb[(size_t)(idx[l + 0] - 1) * 64 + c];
            a0.x += v.x; a0.y += v.y; a0.z += v.z; a0.w += v.w;
        }
        if (idx[l + 1] > 0) {
            const float4 v = *(const float4*)&emb[(size_t)(idx[l + 1] - 1) * 64 + c];
            a1.x += v.x; a1.y += v.y; a1.z += v.z; a1.w += v.w;
        }
        if (idx[l + 2] > 0) {
            const float4 v = *(const float4*)&emb[(size_t)(idx[l + 2] - 1) * 64 + c];
            a2.x += v.x; a2.y += v.y; a2.z += v.z; a2.w += v.w;
        }
        if (idx[l + 3] > 0) {
            const float4 v = *(const float4*)&emb[(size_t)(idx[l + 3] - 1) * 64 + c];
            a3.x += v.x; a3.y += v.y; a3.z += v.z; a3.w += v.w;
        }
    }
    const float inv = 1.0f / (hlen[r] + 1e-15f);
    float4 acc;
    acc.x = (a0.x + a1.x + a2.x + a3.x) * inv;
    acc.y = (a0.y + a1.y + a2.y + a3.y) * inv;
    acc.z = (a0.z + a1.z + a2.z + a3.z) * inv;
    acc.w = (a0.w + a1.w + a2.w + a3.w) * inv;
    *(float4*)&out[(size_t)r * 64 + c] = acc;
}

struct HyeB {
    const float* emb;      // contiguous h2 [4Nn,64]
    const int* hnode[4];
    const float* hlen[4];
    float* out;            // contiguous hemb [4Nn,64]
    int Nn;
};

__global__ __launch_bounds__(256) void hye_b(HyeB a) {
    const int gr = blockIdx.x * 16 + (threadIdx.x >> 4);
    const int c = (threadIdx.x & 15) << 2;
    if (gr >= 4 * a.Nn) return;
    const int g = gr / a.Nn;
    const int lr = gr - g * a.Nn;
    const float* __restrict__ emb = a.emb + (size_t)g * a.Nn * 64;
    const int4* hp4 = (const int4*)&a.hnode[g][(size_t)lr * 16];
    const int4 w0 = hp4[0], w1 = hp4[1], w2 = hp4[2], w3 = hp4[3];
    int idx[16] = {w0.x, w0.y, w0.z, w0.w, w1.x, w1.y, w1.z, w1.w,
                   w2.x, w2.y, w2.z, w2.w, w3.x, w3.y, w3.z, w3.w};
    float4 a0 = make_float4(0.f, 0.f, 0.f, 0.f);
    float4 a1 = make_float4(0.f, 0.f, 0.f, 0.f);
    float4 a2 = make_float4(0.f, 0.f, 0.f, 0.f);
    float4 a3 = make_float4(0.f, 0.f, 0.f, 0.f);
#pragma unroll
    for (int l = 0; l < 16; l += 4) {
        if (idx[l + 0] > 0) {
            const float4 v = *(const float4*)&emb[(size_t)(idx[l + 0] - 1) * 64 + c];
            a0.x += v.x; a0.y += v.y; a0.z += v.z; a0.w += v.w;
        }
        if (idx[l + 1] > 0) {
            const float4 v = *(const float4*)&emb[(size_t)(idx[l + 1] - 1) * 64 + c];
            a1.x += v.x; a1.y += v.y; a1.z += v.z; a1.w += v.w;
        }
        if (idx[l + 2] > 0) {
            const float4 v = *(const float4*)&emb[(size_t)(idx[l + 2] - 1) * 64 + c];
            a2.x += v.x; a2.y += v.y; a2.z += v.z; a2.w += v.w;
        }
        if (idx[l + 3] > 0) {
            const float4 v = *(const float4*)&emb[(size_t)(idx[l + 3] - 1) * 64 + c];
            a3.x += v.x; a3.y += v.y; a3.z += v.z; a3.w += v.w;
        }
    }
    const float inv = 1.0f / (a.hlen[g][lr] + 1e-15f);
    float4 acc;
    acc.x = (a0.x + a1.x + a2.x + a3.x) * inv;
    acc.y = (a0.y + a1.y + a2.y + a3.y) * inv;
    acc.z = (a0.z + a1.z + a2.z + a3.z) * inv;
    acc.w = (a0.w + a1.w + a2.w + a3.w) * inv;
    *(float4*)&a.out[(size_t)gr * 64 + c] = acc;
}

// ---------------------------------------------------------------------------
// Fusion-attention scores
// ---------------------------------------------------------------------------
struct AttnArgs {
    const float* z[8];
    const float* W1c; const float* b1c; const float* W2c;
    const float* W1m; const float* b1m; const float* W2m;
    float* accw;
    int Nn;
};

__global__ __launch_bounds__(256) void attn_gemm(AttnArgs a) {
    __shared__ float As[64][68];    // [k][m], 64 rows
    __shared__ float Bs[64][128];   // [k][h]
    __shared__ float red[4];
    const int tid = threadIdx.x;
    const int gy = blockIdx.y;
    const int head = gy >> 2;
    const float* __restrict__ z  = a.z[gy];
    const float* __restrict__ W1 = head ? a.W1m : a.W1c;
    const float* __restrict__ b1 = head ? a.b1m : a.b1c;
    const float* __restrict__ W2 = head ? a.W2m : a.W2c;
    const int m0 = blockIdx.x * 64;

    {
        const int m = tid >> 2;
        const int qb = tid & 3;
        const int grow = m0 + m;
#pragma unroll
        for (int it = 0; it < 4; it++) {
            const int q = qb + 4 * it;
            float4 v = make_float4(0.f, 0.f, 0.f, 0.f);
            if (grow < a.Nn) v = *(const float4*)&z[(size_t)grow * 64 + q * 4];
            As[q * 4 + 0][m] = v.x;
            As[q * 4 + 1][m] = v.y;
            As[q * 4 + 2][m] = v.z;
            As[q * 4 + 3][m] = v.w;
        }
    }
    {
#pragma unroll
        for (int i = 0; i < 8; i++) {
            const int f = tid + 256 * i;
            const int r = f >> 5, cc = (f & 31) << 2;
            *(float4*)&Bs[r][cc] = *(const float4*)&W1[(size_t)r * 128 + cc];
        }
    }
    __syncthreads();

    const int mq = (tid & 15) << 2;
    const int cq = (tid >> 4) << 2;
    float acc[4][8] = {{0.f}};
    for (int k = 0; k < 64; k++) {
        float av[4], bv[8];
        *(float4*)&av[0] = *(const float4*)&As[k][mq];
        *(float4*)&bv[0] = *(const float4*)&Bs[k][cq];
        *(float4*)&bv[4] = *(const float4*)&Bs[k][cq + 64];
#pragma unroll
        for (int r = 0; r < 4; r++)
#pragma unroll
            for (int c = 0; c < 8; c++)
                acc[r][c] = fmaf(av[r], bv[c], acc[r][c]);
    }

    float w2v[8], b1v[8];
#pragma unroll
    for (int c = 0; c < 8; c++) {
        const int col = cq + (c & 3) + ((c >> 2) << 6);
        w2v[c] = W2[col];
        b1v[c] = b1[col];
    }
    float local = 0.f;
#pragma unroll
    for (int r = 0; r < 4; r++) {
        if (m0 + mq + r < a.Nn) {
#pragma unroll
            for (int c = 0; c < 8; c++) {
                float s = acc[r][c] + b1v[c];
                s = fminf(fmaxf(s, -15.f), 15.f);
                const float t = __expf(2.f * s);
                local += (1.f - 2.f / (t + 1.f)) * w2v[c];
            }
        }
    }
#pragma unroll
    for (int off = 32; off >= 1; off >>= 1) local += __shfl_down(local, off, 64);
    if ((tid & 63) == 0) red[tid >> 6] = local;
    __syncthreads();
    if (tid == 0) atomicAdd(&a.accw[gy], red[0] + red[1] + red[2] + red[3]);
}

__global__ void softmax_beta(const float* __restrict__ acc, float* __restrict__ beta,
                             float invN) {
    const int t = threadIdx.x;
    if (t < 2) {
        const float* a = acc + 4 * t;
        float* b = beta + 4 * t;
        float w[4], m = -1e30f;
#pragma unroll
        for (int i = 0; i < 4; i++) { w[i] = a[i] * invN; m = fmaxf(m, w[i]); }
        float s = 0.f;
#pragma unroll
        for (int i = 0; i < 4; i++) { w[i] = expf(w[i] - m); s += w[i]; }
#pragma unroll
        for (int i = 0; i < 4; i++) b[i] = w[i] / s;
    }
}

__global__ __launch_bounds__(256) void weighted_sum(const float* __restrict__ z0,
                                                    const float* __restrict__ z1,
                                                    const float* __restrict__ z2,
                                                    const float* __restrict__ z3,
                                                    const float* __restrict__ beta,
                                                    float* __restrict__ out, int Nn) {
    const int t = blockIdx.x * 256 + threadIdx.x;
    if (t >= Nn * 16) return;
    const float b0 = beta[0], b1 = beta[1], b2 = beta[2], b3 = beta[3];
    const float4 v0 = *(const float4*)&z0[(size_t)t * 4];
    const float4 v1 = *(const float4*)&z1[(size_t)t * 4];
    const float4 v2 = *(const float4*)&z2[(size_t)t * 4];
    const float4 v3 = *(const float4*)&z3[(size_t)t * 4];
    float4 o;
    o.x = b0 * v0.x + b1 * v1.x + b2 * v2.x + b3 * v3.x;
    o.y = b0 * v0.y + b1 * v1.y + b2 * v2.y + b3 * v3.y;
    o.z = b0 * v0.z + b1 * v1.z + b2 * v2.z + b3 * v3.z;
    o.w = b0 * v0.w + b1 * v1.w + b2 * v2.w + b3 * v3.w;
    *(float4*)&out[(size_t)t * 4] = o;
}

// ---------------------------------------------------------------------------
extern "C" void kernel_launch(void* const* d_in, const int* in_sizes, int n_in,
                              void* d_out, int out_size, void* d_ws, size_t ws_size,
                              hipStream_t stream) {
    const int Nn = in_sizes[0] / NF;   // 50000
    const int E  = in_sizes[1] / 2;    // 800000
    const int N2 = 2 * Nn;

    const float* x[4];
    const int*   ei[4];
    const int*   hnode[4];
    const float* hlen[4];
    for (int g = 0; g < 4; g++) {
        x[g]     = (const float*)d_in[4 * g + 0];
        ei[g]    = (const int*)d_in[4 * g + 1];
        hnode[g] = (const int*)d_in[4 * g + 2];
        hlen[g]  = (const float*)d_in[4 * g + 3];
    }
    const float* W1   = (const float*)d_in[16];
    const float* b1   = (const float*)d_in[17];
    const float* W2   = (const float*)d_in[18];
    const float* b2   = (const float*)d_in[19];
    const float* acW1 = (const float*)d_in[20];
    const float* acb1 = (const float*)d_in[21];
    const float* acW2 = (const float*)d_in[22];
    const float* amW1 = (const float*)d_in[23];
    const float* amb1 = (const float*)d_in[24];
    const float* amW2 = (const float*)d_in[25];

    // ---- batched-path workspace requirement (~183 MB < fallback's ~216 MB) ----
    const size_t fRA   = (size_t)4 * Nn * 64;    // ping: gather128 half-out; later D; later hemb
    const size_t fRB   = (size_t)4 * Nn * 128;   // B2 [4N,128]; later h2 (lo) + E1 (hi)
    const size_t fDinv = (size_t)4 * N2;
    const size_t fcnt  = fRA + fRB + fDinv + 16;
    const size_t icnt  = ((size_t)4 * N2 + 4) + 512 + (size_t)8 * E;
    const size_t need  = (fcnt + icnt) * sizeof(float) + 256;
    const bool raFitsInts = fRA * sizeof(float) >=
                            ((size_t)4 * N2 + (size_t)4 * E) * sizeof(int);

    if (need <= ws_size && raFitsInts) {
        // =================== batched path ===================
        float* ws = (float*)d_ws;
        size_t o = 0;
        float* RA   = ws + o; o += fRA;   // [2N,128] ping == [4N,64]
        float* RB   = ws + o; o += fRB;   // [4N,128]
        float* dinv = ws + o; o += fDinv;
        float* accw = ws + o; o += 8;
        float* beta = ws + o; o += 8;
        int* iws = (int*)(ws + o);
        size_t io = 0;
        int* off      = iws + io; io += (size_t)4 * N2 + 4;
        int* partials = iws + io; io += 512;
        int* srcidx   = iws + io; io += (size_t)8 * E;
        // transient build ints aliased into RA (dead before RA's first write)
        int* deg  = (int*)RA;
        int* rank = deg + (size_t)4 * N2;

        const int n8 = 4 * N2;                     // 400000
        const int nScanBlocks = cdiv(n8, 1024);    // 391 <= 512

        BuildB bb;
        for (int g = 0; g < 4; g++) { bb.nidx[g] = ei[g]; bb.eidx[g] = ei[g] + E; }
        bb.deg = deg; bb.rank = rank; bb.off = off; bb.srcidx = srcidx;
        bb.Nn = Nn; bb.E = E; bb.shardSize = cdiv(Nn, 8);

        hipMemsetAsync(deg, 0, (size_t)n8 * sizeof(int), stream);
        count_rank_b<<<dim3(cdiv(E, 256), 4), 256, 0, stream>>>(bb);
        scan_blocks<<<nScanBlocks, 256, 0, stream>>>(deg, off, partials, n8);
        scan_partials<<<1, 512, 0, stream>>>(partials, nScanBlocks);
        scan_add<<<cdiv(n8, 256), 256, 0, stream>>>(off, partials, n8, 2 * 4 * E);
        build_fill_b<<<dim3(8 * cdiv(E, 1024), 4), 256, 0, stream>>>(bb);
        invert_deg_int<<<cdiv(n8, 256), 256, 0, stream>>>(deg, dinv, n8);
        // RA's int aliases (deg/rank) are now dead.

        // ---- hconv1 gathers, two 2-graph halves through RA ----
        const int gh = cdiv(2 * Nn, 16);
        for (int h = 0; h < 2; h++) {
            const int gb = 2 * h;
            Gather128H p1;
            p1.src[0] = x[gb]; p1.src[1] = x[gb + 1];
            p1.dst = RA; p1.off = off; p1.srcidx = srcidx;
            p1.dinv = dinv; p1.gbase = gb; p1.passBase = Nn; p1.Nn = Nn;  // edge, b_inv
            gather128_h<<<gh, 256, 0, stream>>>(p1);

            Gather128H p2;
            p2.src[0] = RA; p2.src[1] = RA + (size_t)Nn * 128;
            p2.dst = RB + (size_t)gb * Nn * 128;
            p2.off = off; p2.srcidx = srcidx;
            p2.dinv = nullptr; p2.gbase = gb; p2.passBase = 0; p2.Nn = Nn; // node
            gather128_h<<<gh, 256, 0, stream>>>(p2);
        }

        // ---- fused hconv1-GEMM + hconv2-GEMM: RB -> D (in RA) ----
        float* Dbuf = RA;   // [4N,64], RA fully dead-written
        Gemm12B gm;
        gm.A = RB; gm.W1 = W1; gm.W2 = W2; gm.b1 = b1;
        gm.dinv = dinv; gm.D = Dbuf; gm.Nn = Nn;
        gemm12_b<<<cdiv(4 * Nn, 64), 256, 0, stream>>>(gm);

        // ---- hconv2 gathers ----
        float* E1  = RB + (size_t)4 * Nn * 64;   // RB upper half [4N,64]
        float* h2b = RB;                          // RB lower half [4N,64]
        Gather64B g3;
        for (int g = 0; g < 4; g++) g3.src[g] = Dbuf + (size_t)g * Nn * 64;
        g3.dst = E1; g3.off = off; g3.srcidx = srcidx;
        g3.dinv = dinv; g3.post_bias = nullptr; g3.passBase = Nn; g3.Nn = Nn;
        gather64_b<<<cdiv(4 * Nn, 32), 256, 0, stream>>>(g3);

        Gather64B g4;
        for (int g = 0; g < 4; g++) g4.src[g] = E1 + (size_t)g * Nn * 64;
        g4.dst = h2b; g4.off = off; g4.srcidx = srcidx;
        g4.dinv = dinv; g4.post_bias = b2; g4.passBase = 0; g4.Nn = Nn;
        gather64_b<<<cdiv(4 * Nn, 32), 256, 0, stream>>>(g4);

        // ---- hyperedge embedding: h2b (RB lo) -> hemb (RA, D dead) ----
        float* hembb = RA;
        HyeB hb;
        hb.emb = h2b;
        for (int g = 0; g < 4; g++) { hb.hnode[g] = hnode[g]; hb.hlen[g] = hlen[g]; }
        hb.out = hembb; hb.Nn = Nn;
        hye_b<<<cdiv(4 * Nn, 16), 256, 0, stream>>>(hb);

        // ---- fusion attention ----
        const size_t st = (size_t)Nn * 64;
        hipMemsetAsync(accw, 0, 8 * sizeof(float), stream);
        AttnArgs aa;
        aa.z[0] = h2b + 1 * st; aa.z[1] = hembb + 0 * st;
        aa.z[2] = h2b + 2 * st; aa.z[3] = hembb + 2 * st;
        aa.z[4] = h2b + 0 * st; aa.z[5] = hembb + 1 * st;
        aa.z[6] = h2b + 3 * st; aa.z[7] = hembb + 3 * st;
        aa.W1c = acW1; aa.b1c = acb1; aa.W2c = acW2;
        aa.W1m = amW1; aa.b1m = amb1; aa.W2m = amW2;
        aa.accw = accw; aa.Nn = Nn;
        attn_gemm<<<dim3(cdiv(Nn, 64), 8), 256, 0, stream>>>(aa);
        softmax_beta<<<1, 64, 0, stream>>>(accw, beta, 1.0f / (float)Nn);

        float* out = (float*)d_out;
        weighted_sum<<<cdiv(Nn * 16, 256), 256, 0, stream>>>(
            aa.z[0], aa.z[1], aa.z[2], aa.z[3], beta + 0, out, Nn);
        weighted_sum<<<cdiv(Nn * 16, 256), 256, 0, stream>>>(
            aa.z[4], aa.z[5], aa.z[6], aa.z[7], beta + 4, out + (size_t)Nn * DD2, Nn);
        return;
    }

    // =================== fallback: proven per-graph path ===================
    float* ws = (float*)d_ws;
    size_t o = 0;
    float* bufA = ws + o; o += (size_t)Nn * DD1;
    float* bufB = ws + o; o += (size_t)Nn * DD1;
    float* dinv = ws + o; o += N2;
    float* h2[4];
    float* hemb[4];
    for (int g = 0; g < 4; g++) { h2[g]   = ws + o; o += (size_t)Nn * DD2; }
    for (int g = 0; g < 4; g++) { hemb[g] = ws + o; o += (size_t)Nn * DD2; }
    float* accw = ws + o; o += 8;
    float* beta = ws + o; o += 8;
    int* iws = (int*)(ws + o);
    size_t io = 0;
    int* deg_i    = iws + io; io += N2;
    int* off      = iws + io; io += N2 + 1;
    int* partials = iws + io; io += 512;
    int* rank     = iws + io; io += E;
    int* srcidx   = iws + io; io += (size_t)2 * E;

    const int nScanBlocks = cdiv(N2, 1024);
    const int shardSize = cdiv(Nn, 8);

    for (int g = 0; g < 4; g++) {
        const int* nidx = ei[g];
        const int* eidx = ei[g] + E;
        const int* off_n = off;
        const int* off_e = off + Nn;
        const float* d_inv = dinv;
        const float* b_inv = dinv + Nn;

        hipMemsetAsync(deg_i, 0, (size_t)N2 * sizeof(int), stream);
        count_rank<<<cdiv(E, 256), 256, 0, stream>>>(nidx, eidx, deg_i, rank, Nn, E);
        scan_blocks<<<nScanBlocks, 256, 0, stream>>>(deg_i, off, partials, N2);
        scan_partials<<<1, 512, 0, stream>>>(partials, nScanBlocks);
        scan_add<<<cdiv(N2, 256), 256, 0, stream>>>(off, partials, N2, 2 * E);
        build_fill<<<8 * cdiv(E, 1024), 256, 0, stream>>>(nidx, eidx, rank, off,
                                                          srcidx, Nn, E, shardSize);
        invert_deg_int<<<cdiv(N2, 256), 256, 0, stream>>>(deg_i, dinv, N2);

        gather_rows_128<<<cdiv(Nn, 16), 256, 0, stream>>>(x[g], off_e, srcidx, b_inv, bufB, Nn);
        gather_rows_128<<<cdiv(Nn, 16), 256, 0, stream>>>(bufB, off_n, srcidx, nullptr, bufA, Nn);
        gemm1_f32<<<dim3(2, cdiv(Nn, 128)), 256, 0, stream>>>(bufA, W1, bufB, Nn, d_inv, b1);

        gemm2_f32<<<dim3(1, cdiv(Nn, 128)), 256, 0, stream>>>(bufB, W2, bufA, Nn);
        gather_rows_64<<<cdiv(Nn, 32), 256, 0, stream>>>(bufA, off_e, srcidx, b_inv,
                                                         nullptr, bufB, Nn);
        gather_rows_64<<<cdiv(Nn, 32), 256, 0, stream>>>(bufB, off_n, srcidx, d_inv,
                                                         b2, h2[g], Nn);

        hye_emb_kernel<<<cdiv(Nn, 16), 256, 0, stream>>>(h2[g], hnode[g], hlen[g], hemb[g], Nn);
    }

    hipMemsetAsync(accw, 0, 8 * sizeof(float), stream);
    AttnArgs aa;
    aa.z[0] = h2[1]; aa.z[1] = hemb[0]; aa.z[2] = h2[2]; aa.z[3] = hemb[2];
    aa.z[4] = h2[0]; aa.z[5] = hemb[1]; aa.z[6] = h2[3]; aa.z[7] = hemb[3];
    aa.W1c = acW1; aa.b1c = acb1; aa.W2c = acW2;
    aa.W1m = amW1; aa.b1m = amb1; aa.W2m = amW2;
    aa.accw = accw; aa.Nn = Nn;
    attn_gemm<<<dim3(cdiv(Nn, 64), 8), 256, 0, stream>>>(aa);
    softmax_beta<<<1, 64, 0, stream>>>(accw, beta, 1.0f / (float)Nn);

    float* out = (float*)d_out;
    weighted_sum<<<cdiv(Nn * 16, 256), 256, 0, stream>>>(h2[1], hemb[0], h2[2], hemb[2],
                                                         beta + 0, out, Nn);
    weighted_sum<<<cdiv(Nn * 16, 256), 256, 0, stream>>>(h2[0], hemb[1], h2[3], hemb[3],
                                                         beta + 4, out + (size_t)Nn * DD2, Nn);
}

// Round 5
// 1659.711 us; speedup vs baseline: 1.1638x; 1.1638x over previous
//
#include <hip/hip_runtime.h>
#include <hip/hip_bf16.h>

// Problem constants
#define NF   128   // in_channels
#define DD1  256   // dim_1
#define DD2  64    // dim_1/4
#define HATT 128   // attention hidden

static inline int cdiv(int a, int b) { return (a + b - 1) / b; }

// ---------------------------------------------------------------------------
// Pass 1: degree count + per-edge rank capture (rank < 2^16 since max deg ~45).
// ---------------------------------------------------------------------------
__global__ __launch_bounds__(256) void count_rank(const int* __restrict__ nidx,
                                                  const int* __restrict__ eidx,
                                                  int* __restrict__ deg,
                                                  int* __restrict__ rank,
                                                  int N, int E) {
    int e = blockIdx.x * 256 + threadIdx.x;
    if (e < E) {
        const int vn = nidx[e], ve = eidx[e];
        const int rn = atomicAdd(&deg[vn], 1);
        const int re = atomicAdd(&deg[N + ve], 1);
        rank[e] = rn | (re << 16);
    }
}

__global__ __launch_bounds__(256) void scan_blocks(const int* __restrict__ in,
                                                   int* __restrict__ out,
                                                   int* __restrict__ partials, int n) {
    __shared__ int s[256];
    const int base = blockIdx.x * 1024;
    const int t = threadIdx.x;
    int v[4], sum = 0;
#pragma unroll
    for (int i = 0; i < 4; i++) {
        const int idx = base + t * 4 + i;
        v[i] = (idx < n) ? in[idx] : 0;
        sum += v[i];
    }
    s[t] = sum;
    __syncthreads();
    for (int o = 1; o < 256; o <<= 1) {
        int x = 0;
        if (t >= o) x = s[t - o];
        __syncthreads();
        if (t >= o) s[t] += x;
        __syncthreads();
    }
    if (t == 255) partials[blockIdx.x] = s[255];
    int run = (t == 0) ? 0 : s[t - 1];
#pragma unroll
    for (int i = 0; i < 4; i++) {
        const int idx = base + t * 4 + i;
        if (idx < n) out[idx] = run;
        run += v[i];
    }
}

// 512 threads: handles up to 512 partials (batched path needs 391).
__global__ __launch_bounds__(512) void scan_partials(int* __restrict__ partials, int P) {
    __shared__ int s[512];
    const int t = threadIdx.x;
    s[t] = (t < P) ? partials[t] : 0;
    __syncthreads();
    for (int o = 1; o < 512; o <<= 1) {
        int x = 0;
        if (t >= o) x = s[t - o];
        __syncthreads();
        if (t >= o) s[t] += x;
        __syncthreads();
    }
    if (t < P) partials[t] = (t == 0) ? 0 : s[t - 1];
}

__global__ __launch_bounds__(256) void scan_add(int* __restrict__ off,
                                                const int* __restrict__ partials,
                                                int n, int total) {
    const int idx = blockIdx.x * 256 + threadIdx.x;
    if (idx < n) off[idx] += partials[idx >> 10];
    if (idx == 0) off[n] = total;
}

// ---------------------------------------------------------------------------
// Pass 2: store-only CSR fill, sharded by destination-vertex range.
// ---------------------------------------------------------------------------
__global__ __launch_bounds__(256) void build_fill(const int* __restrict__ nidx,
                                                  const int* __restrict__ eidx,
                                                  const int* __restrict__ rank,
                                                  const int* __restrict__ off,
                                                  int* __restrict__ srcidx,
                                                  int N, int E, int shardSize) {
    const int shard = blockIdx.x & 7;
    const int chunk = blockIdx.x >> 3;
    const int lo = shard * shardSize;
    const int hi = lo + shardSize;
    const int base = chunk * 1024;
#pragma unroll
    for (int i = 0; i < 4; i++) {
        const int e = base + i * 256 + threadIdx.x;
        if (e < E) {
            const int vn = nidx[e], ve = eidx[e];
            const int rk = rank[e];
            if (vn >= lo && vn < hi)
                srcidx[off[vn] + (rk & 0xffff)] = ve;
            if (ve >= lo && ve < hi)
                srcidx[off[N + ve] + (rk >> 16)] = vn;
        }
    }
}

__global__ __launch_bounds__(256) void invert_deg_int(const int* __restrict__ deg,
                                                      float* __restrict__ inv, int n) {
    int t = blockIdx.x * 256 + threadIdx.x;
    if (t < n) {
        const int v = deg[t];
        inv[t] = (v > 0) ? 1.0f / (float)v : 0.f;
    }
}

// ===========================================================================
// Batched (4-graph) CSR build. One scan over the concatenated degree arrays
// gives GLOBAL offsets into a single srcidx[8E].
// ===========================================================================
struct BuildB {
    const int* nidx[4];
    const int* eidx[4];
    int* deg;        // [4 * 2N]  (transient, aliased into RA)
    int* rank;       // [4 * E]   (transient, aliased into RA)
    const int* off;  // [4 * 2N + 1] global offsets
    int* srcidx;     // [4 * 2E]
    int Nn, E, shardSize;
};

__global__ __launch_bounds__(256) void count_rank_b(BuildB a) {
    const int g = blockIdx.y;
    const int e = blockIdx.x * 256 + threadIdx.x;
    if (e < a.E) {
        const int vn = a.nidx[g][e], ve = a.eidx[g][e];
        int* dg = a.deg + (size_t)g * 2 * a.Nn;
        const int rn = atomicAdd(&dg[vn], 1);
        const int re = atomicAdd(&dg[a.Nn + ve], 1);
        a.rank[(size_t)g * a.E + e] = rn | (re << 16);
    }
}

__global__ __launch_bounds__(256) void build_fill_b(BuildB a) {
    const int g = blockIdx.y;
    const int shard = blockIdx.x & 7;
    const int chunk = blockIdx.x >> 3;
    const int lo = shard * a.shardSize;
    const int hi = lo + a.shardSize;
    const int base = chunk * 1024;
    const int* __restrict__ nidx = a.nidx[g];
    const int* __restrict__ eidx = a.eidx[g];
    const int* __restrict__ rank = a.rank + (size_t)g * a.E;
    const int* __restrict__ off  = a.off + (size_t)g * 2 * a.Nn;
#pragma unroll
    for (int i = 0; i < 4; i++) {
        const int e = base + i * 256 + threadIdx.x;
        if (e < a.E) {
            const int vn = nidx[e], ve = eidx[e];
            const int rk = rank[e];
            if (vn >= lo && vn < hi)
                a.srcidx[off[vn] + (rk & 0xffff)] = ve;
            if (ve >= lo && ve < hi)
                a.srcidx[off[a.Nn + ve] + (rk >> 16)] = vn;
        }
    }
}

// ---------------------------------------------------------------------------
// CSR gather, D=128 (per-graph, fallback path).
// ---------------------------------------------------------------------------
__global__ __launch_bounds__(256) void gather_rows_128(const float* __restrict__ src,
                                                       const int* __restrict__ off,
                                                       const int* __restrict__ srcidx,
                                                       const float* __restrict__ scale,
                                                       float* __restrict__ dst, int Nn) {
    const int row = blockIdx.x * 16 + (threadIdx.x >> 4);
    if (row >= Nn) return;
    const int c = (threadIdx.x & 15) << 2;
    const int j0 = off[row], j1 = off[row + 1];
    float4 pa = make_float4(0.f, 0.f, 0.f, 0.f);
    float4 pb = make_float4(0.f, 0.f, 0.f, 0.f);
    float4 qa = make_float4(0.f, 0.f, 0.f, 0.f);
    float4 qb = make_float4(0.f, 0.f, 0.f, 0.f);
    int j = j0;
    for (; j + 3 < j1; j += 4) {
        const int s0 = srcidx[j + 0];
        const int s1 = srcidx[j + 1];
        const int s2 = srcidx[j + 2];
        const int s3 = srcidx[j + 3];
        const float4 v0a = *(const float4*)&src[(size_t)s0 * 128 + c];
        const float4 v0b = *(const float4*)&src[(size_t)s0 * 128 + c + 64];
        const float4 v1a = *(const float4*)&src[(size_t)s1 * 128 + c];
        const float4 v1b = *(const float4*)&src[(size_t)s1 * 128 + c + 64];
        const float4 v2a = *(const float4*)&src[(size_t)s2 * 128 + c];
        const float4 v2b = *(const float4*)&src[(size_t)s2 * 128 + c + 64];
        const float4 v3a = *(const float4*)&src[(size_t)s3 * 128 + c];
        const float4 v3b = *(const float4*)&src[(size_t)s3 * 128 + c + 64];
        pa.x += v0a.x + v1a.x; pa.y += v0a.y + v1a.y;
        pa.z += v0a.z + v1a.z; pa.w += v0a.w + v1a.w;
        qa.x += v2a.x + v3a.x; qa.y += v2a.y + v3a.y;
        qa.z += v2a.z + v3a.z; qa.w += v2a.w + v3a.w;
        pb.x += v0b.x + v1b.x; pb.y += v0b.y + v1b.y;
        pb.z += v0b.z + v1b.z; pb.w += v0b.w + v1b.w;
        qb.x += v2b.x + v3b.x; qb.y += v2b.y + v3b.y;
        qb.z += v2b.z + v3b.z; qb.w += v2b.w + v3b.w;
    }
    for (; j < j1; j++) {
        const int s0 = srcidx[j];
        const float4 va = *(const float4*)&src[(size_t)s0 * 128 + c];
        const float4 vb = *(const float4*)&src[(size_t)s0 * 128 + c + 64];
        pa.x += va.x; pa.y += va.y; pa.z += va.z; pa.w += va.w;
        pb.x += vb.x; pb.y += vb.y; pb.z += vb.z; pb.w += vb.w;
    }
    float4 aca = make_float4(pa.x + qa.x, pa.y + qa.y, pa.z + qa.z, pa.w + qa.w);
    float4 acb = make_float4(pb.x + qb.x, pb.y + qb.y, pb.z + qb.z, pb.w + qb.w);
    if (scale) {
        const float s = scale[row];
        aca.x *= s; aca.y *= s; aca.z *= s; aca.w *= s;
        acb.x *= s; acb.y *= s; acb.z *= s; acb.w *= s;
    }
    *(float4*)&dst[(size_t)row * 128 + c] = aca;
    *(float4*)&dst[(size_t)row * 128 + c + 64] = acb;
}

// Half-batched variant: TWO graphs per launch so the ping buffer is [2N,128].
struct Gather128H {
    const float* src[2];       // per-graph source base (local rows)
    float* dst;                // contiguous [2*Nn][128] from dst
    const int* off;            // global off [8N+1]
    const int* srcidx;
    const float* dinv;         // global [8N] or nullptr
    int gbase;                 // 0 or 2
    int passBase;              // 0 = node CSR, Nn = edge CSR
    int Nn;
};

__global__ __launch_bounds__(256) void gather128_h(Gather128H a) {
    const int gr = blockIdx.x * 16 + (threadIdx.x >> 4);
    if (gr >= 2 * a.Nn) return;
    const int gl = gr / a.Nn;              // 0/1 within this half
    const int row = gr - gl * a.Nn;
    const float* __restrict__ src = a.src[gl];
    const int ob = (a.gbase + gl) * 2 * a.Nn + a.passBase + row;
    const int c = (threadIdx.x & 15) << 2;
    const int j0 = a.off[ob], j1 = a.off[ob + 1];
    float4 pa = make_float4(0.f, 0.f, 0.f, 0.f);
    float4 pb = make_float4(0.f, 0.f, 0.f, 0.f);
    float4 qa = make_float4(0.f, 0.f, 0.f, 0.f);
    float4 qb = make_float4(0.f, 0.f, 0.f, 0.f);
    int j = j0;
    for (; j + 3 < j1; j += 4) {
        const int s0 = a.srcidx[j + 0];
        const int s1 = a.srcidx[j + 1];
        const int s2 = a.srcidx[j + 2];
        const int s3 = a.srcidx[j + 3];
        const float4 v0a = *(const float4*)&src[(size_t)s0 * 128 + c];
        const float4 v0b = *(const float4*)&src[(size_t)s0 * 128 + c + 64];
        const float4 v1a = *(const float4*)&src[(size_t)s1 * 128 + c];
        const float4 v1b = *(const float4*)&src[(size_t)s1 * 128 + c + 64];
        const float4 v2a = *(const float4*)&src[(size_t)s2 * 128 + c];
        const float4 v2b = *(const float4*)&src[(size_t)s2 * 128 + c + 64];
        const float4 v3a = *(const float4*)&src[(size_t)s3 * 128 + c];
        const float4 v3b = *(const float4*)&src[(size_t)s3 * 128 + c + 64];
        pa.x += v0a.x + v1a.x; pa.y += v0a.y + v1a.y;
        pa.z += v0a.z + v1a.z; pa.w += v0a.w + v1a.w;
        qa.x += v2a.x + v3a.x; qa.y += v2a.y + v3a.y;
        qa.z += v2a.z + v3a.z; qa.w += v2a.w + v3a.w;
        pb.x += v0b.x + v1b.x; pb.y += v0b.y + v1b.y;
        pb.z += v0b.z + v1b.z; pb.w += v0b.w + v1b.w;
        qb.x += v2b.x + v3b.x; qb.y += v2b.y + v3b.y;
        qb.z += v2b.z + v3b.z; qb.w += v2b.w + v3b.w;
    }
    for (; j < j1; j++) {
        const int s0 = a.srcidx[j];
        const float4 va = *(const float4*)&src[(size_t)s0 * 128 + c];
        const float4 vb = *(const float4*)&src[(size_t)s0 * 128 + c + 64];
        pa.x += va.x; pa.y += va.y; pa.z += va.z; pa.w += va.w;
        pb.x += vb.x; pb.y += vb.y; pb.z += vb.z; pb.w += vb.w;
    }
    float4 aca = make_float4(pa.x + qa.x, pa.y + qa.y, pa.z + qa.z, pa.w + qa.w);
    float4 acb = make_float4(pb.x + qb.x, pb.y + qb.y, pb.z + qb.z, pb.w + qb.w);
    if (a.dinv) {
        const float s = a.dinv[ob];
        aca.x *= s; aca.y *= s; aca.z *= s; aca.w *= s;
        acb.x *= s; acb.y *= s; acb.z *= s; acb.w *= s;
    }
    *(float4*)&a.dst[(size_t)gr * 128 + c] = aca;
    *(float4*)&a.dst[(size_t)gr * 128 + c + 64] = acb;
}

// ---------------------------------------------------------------------------
// CSR gather, D=64 (per-graph fallback).
// ---------------------------------------------------------------------------
__global__ __launch_bounds__(256) void gather_rows_64(const float* __restrict__ src,
                                                      const int* __restrict__ off,
                                                      const int* __restrict__ srcidx,
                                                      const float* __restrict__ scale,
                                                      const float* __restrict__ post_bias,
                                                      float* __restrict__ dst, int Nn) {
    const int row = blockIdx.x * 32 + (threadIdx.x >> 3);
    if (row >= Nn) return;
    const int c = (threadIdx.x & 7) << 2;
    const int j0 = off[row], j1 = off[row + 1];
    float4 pa = make_float4(0.f, 0.f, 0.f, 0.f);
    float4 pb = make_float4(0.f, 0.f, 0.f, 0.f);
    float4 qa = make_float4(0.f, 0.f, 0.f, 0.f);
    float4 qb = make_float4(0.f, 0.f, 0.f, 0.f);
    int j = j0;
    for (; j + 3 < j1; j += 4) {
        const int s0 = srcidx[j + 0];
        const int s1 = srcidx[j + 1];
        const int s2 = srcidx[j + 2];
        const int s3 = srcidx[j + 3];
        const float4 v0a = *(const float4*)&src[(size_t)s0 * 64 + c];
        const float4 v0b = *(const float4*)&src[(size_t)s0 * 64 + c + 32];
        const float4 v1a = *(const float4*)&src[(size_t)s1 * 64 + c];
        const float4 v1b = *(const float4*)&src[(size_t)s1 * 64 + c + 32];
        const float4 v2a = *(const float4*)&src[(size_t)s2 * 64 + c];
        const float4 v2b = *(const float4*)&src[(size_t)s2 * 64 + c + 32];
        const float4 v3a = *(const float4*)&src[(size_t)s3 * 64 + c];
        const float4 v3b = *(const float4*)&src[(size_t)s3 * 64 + c + 32];
        pa.x += v0a.x + v1a.x; pa.y += v0a.y + v1a.y;
        pa.z += v0a.z + v1a.z; pa.w += v0a.w + v1a.w;
        qa.x += v2a.x + v3a.x; qa.y += v2a.y + v3a.y;
        qa.z += v2a.z + v3a.z; qa.w += v2a.w + v3a.w;
        pb.x += v0b.x + v1b.x; pb.y += v0b.y + v1b.y;
        pb.z += v0b.z + v1b.z; pb.w += v0b.w + v1b.w;
        qb.x += v2b.x + v3b.x; qb.y += v2b.y + v3b.y;
        qb.z += v2b.z + v3b.z; qb.w += v2b.w + v3b.w;
    }
    for (; j < j1; j++) {
        const int s0 = srcidx[j];
        const float4 va = *(const float4*)&src[(size_t)s0 * 64 + c];
        const float4 vb = *(const float4*)&src[(size_t)s0 * 64 + c + 32];
        pa.x += va.x; pa.y += va.y; pa.z += va.z; pa.w += va.w;
        pb.x += vb.x; pb.y += vb.y; pb.z += vb.z; pb.w += vb.w;
    }
    float4 aca = make_float4(pa.x + qa.x, pa.y + qa.y, pa.z + qa.z, pa.w + qa.w);
    float4 acb = make_float4(pb.x + qb.x, pb.y + qb.y, pb.z + qb.z, pb.w + qb.w);
    if (scale) {
        const float s = scale[row];
        aca.x *= s; aca.y *= s; aca.z *= s; aca.w *= s;
        acb.x *= s; acb.y *= s; acb.z *= s; acb.w *= s;
    }
    if (post_bias) {
        aca.x = fmaxf(aca.x + post_bias[c + 0], 0.f);
        aca.y = fmaxf(aca.y + post_bias[c + 1], 0.f);
        aca.z = fmaxf(aca.z + post_bias[c + 2], 0.f);
        aca.w = fmaxf(aca.w + post_bias[c + 3], 0.f);
        acb.x = fmaxf(acb.x + post_bias[c + 32], 0.f);
        acb.y = fmaxf(acb.y + post_bias[c + 33], 0.f);
        acb.z = fmaxf(acb.z + post_bias[c + 34], 0.f);
        acb.w = fmaxf(acb.w + post_bias[c + 35], 0.f);
    }
    *(float4*)&dst[(size_t)row * 64 + c] = aca;
    *(float4*)&dst[(size_t)row * 64 + c + 32] = acb;
}

struct Gather64B {
    const float* src[4];
    float* dst;                // contiguous [4*Nn][64]
    const int* off;
    const int* srcidx;
    const float* dinv;         // global [8N] or nullptr
    const float* post_bias;    // nullptr or b2 (fused relu)
    int passBase;
    int Nn;
};

__global__ __launch_bounds__(256) void gather64_b(Gather64B a) {
    const int gr = blockIdx.x * 32 + (threadIdx.x >> 3);
    if (gr >= 4 * a.Nn) return;
    const int g = gr / a.Nn;
    const int row = gr - g * a.Nn;
    const float* __restrict__ src = a.src[g];
    const int ob = g * 2 * a.Nn + a.passBase + row;
    const int c = (threadIdx.x & 7) << 2;
    const int j0 = a.off[ob], j1 = a.off[ob + 1];
    float4 pa = make_float4(0.f, 0.f, 0.f, 0.f);
    float4 pb = make_float4(0.f, 0.f, 0.f, 0.f);
    float4 qa = make_float4(0.f, 0.f, 0.f, 0.f);
    float4 qb = make_float4(0.f, 0.f, 0.f, 0.f);
    int j = j0;
    for (; j + 3 < j1; j += 4) {
        const int s0 = a.srcidx[j + 0];
        const int s1 = a.srcidx[j + 1];
        const int s2 = a.srcidx[j + 2];
        const int s3 = a.srcidx[j + 3];
        const float4 v0a = *(const float4*)&src[(size_t)s0 * 64 + c];
        const float4 v0b = *(const float4*)&src[(size_t)s0 * 64 + c + 32];
        const float4 v1a = *(const float4*)&src[(size_t)s1 * 64 + c];
        const float4 v1b = *(const float4*)&src[(size_t)s1 * 64 + c + 32];
        const float4 v2a = *(const float4*)&src[(size_t)s2 * 64 + c];
        const float4 v2b = *(const float4*)&src[(size_t)s2 * 64 + c + 32];
        const float4 v3a = *(const float4*)&src[(size_t)s3 * 64 + c];
        const float4 v3b = *(const float4*)&src[(size_t)s3 * 64 + c + 32];
        pa.x += v0a.x + v1a.x; pa.y += v0a.y + v1a.y;
        pa.z += v0a.z + v1a.z; pa.w += v0a.w + v1a.w;
        qa.x += v2a.x + v3a.x; qa.y += v2a.y + v3a.y;
        qa.z += v2a.z + v3a.z; qa.w += v2a.w + v3a.w;
        pb.x += v0b.x + v1b.x; pb.y += v0b.y + v1b.y;
        pb.z += v0b.z + v1b.z; pb.w += v0b.w + v1b.w;
        qb.x += v2b.x + v3b.x; qb.y += v2b.y + v3b.y;
        qb.z += v2b.z + v3b.z; qb.w += v2b.w + v3b.w;
    }
    for (; j < j1; j++) {
        const int s0 = a.srcidx[j];
        const float4 va = *(const float4*)&src[(size_t)s0 * 64 + c];
        const float4 vb = *(const float4*)&src[(size_t)s0 * 64 + c + 32];
        pa.x += va.x; pa.y += va.y; pa.z += va.z; pa.w += va.w;
        pb.x += vb.x; pb.y += vb.y; pb.z += vb.z; pb.w += vb.w;
    }
    float4 aca = make_float4(pa.x + qa.x, pa.y + qa.y, pa.z + qa.z, pa.w + qa.w);
    float4 acb = make_float4(pb.x + qb.x, pb.y + qb.y, pb.z + qb.z, pb.w + qb.w);
    if (a.dinv) {
        const float s = a.dinv[ob];
        aca.x *= s; aca.y *= s; aca.z *= s; aca.w *= s;
        acb.x *= s; acb.y *= s; acb.z *= s; acb.w *= s;
    }
    if (a.post_bias) {
        aca.x = fmaxf(aca.x + a.post_bias[c + 0], 0.f);
        aca.y = fmaxf(aca.y + a.post_bias[c + 1], 0.f);
        aca.z = fmaxf(aca.z + a.post_bias[c + 2], 0.f);
        aca.w = fmaxf(aca.w + a.post_bias[c + 3], 0.f);
        acb.x = fmaxf(acb.x + a.post_bias[c + 32], 0.f);
        acb.y = fmaxf(acb.y + a.post_bias[c + 33], 0.f);
        acb.z = fmaxf(acb.z + a.post_bias[c + 34], 0.f);
        acb.w = fmaxf(acb.w + a.post_bias[c + 35], 0.f);
    }
    *(float4*)&a.dst[(size_t)gr * 64 + c] = aca;
    *(float4*)&a.dst[(size_t)gr * 64 + c + 32] = acb;
}

// ---------------------------------------------------------------------------
// GEMM1 (fallback): C[M,256] = relu(dinv[row] * (A[M,128] @ B[128,256]) + bias)
// ---------------------------------------------------------------------------
__global__ __launch_bounds__(256) void gemm1_f32(const float* __restrict__ A,
                                                 const float* __restrict__ B,
                                                 float* __restrict__ C, int M,
                                                 const float* __restrict__ dinv,
                                                 const float* __restrict__ bias) {
    __shared__ float As[32][132];   // [k][m]
    __shared__ float Bs[32][128];   // [k][n]
    const int tid = threadIdx.x;
    const int m0 = blockIdx.y * 128;
    const int bn = blockIdx.x * 128;
    const int rq = (tid >> 4) << 2;
    const int cq = (tid & 15) << 2;

    float acc[8][8] = {{0.f}};

    for (int k0 = 0; k0 < 128; k0 += 32) {
#pragma unroll
        for (int i = 0; i < 4; i++) {
            const int f = tid + 256 * i;
            const int r = f >> 3;
            const int q = (f & 7) << 2;
            const int grow = m0 + r;
            float4 v = make_float4(0.f, 0.f, 0.f, 0.f);
            if (grow < M) v = *(const float4*)&A[(size_t)grow * 128 + k0 + q];
            As[q + 0][r] = v.x;
            As[q + 1][r] = v.y;
            As[q + 2][r] = v.z;
            As[q + 3][r] = v.w;
        }
#pragma unroll
        for (int i = 0; i < 4; i++) {
            const int f = tid + 256 * i;
            const int r = f >> 5;
            const int c4 = (f & 31) << 2;
            *(float4*)&Bs[r][c4] = *(const float4*)&B[(size_t)(k0 + r) * 256 + bn + c4];
        }
        __syncthreads();
#pragma unroll
        for (int k = 0; k < 32; k++) {
            float av[8], bv[8];
            *(float4*)&av[0] = *(const float4*)&As[k][rq];
            *(float4*)&av[4] = *(const float4*)&As[k][rq + 64];
            *(float4*)&bv[0] = *(const float4*)&Bs[k][cq];
            *(float4*)&bv[4] = *(const float4*)&Bs[k][cq + 64];
#pragma unroll
            for (int r = 0; r < 8; r++)
#pragma unroll
                for (int c = 0; c < 8; c++)
                    acc[r][c] = fmaf(av[r], bv[c], acc[r][c]);
        }
        __syncthreads();
    }
#pragma unroll
    for (int r = 0; r < 8; r++) {
        const int grow = m0 + rq + (r & 3) + ((r >> 2) << 6);
        if (grow < M) {
            const float s = dinv[grow];
            float o[8];
#pragma unroll
            for (int c = 0; c < 4; c++)
                o[c] = fmaxf(fmaf(acc[r][c], s, bias[bn + cq + c]), 0.f);
#pragma unroll
            for (int c = 4; c < 8; c++)
                o[c] = fmaxf(fmaf(acc[r][c], s, bias[bn + 64 + cq + (c - 4)]), 0.f);
            *(float4*)&C[(size_t)grow * 256 + bn + cq] = *(float4*)&o[0];
            *(float4*)&C[(size_t)grow * 256 + bn + 64 + cq] = *(float4*)&o[4];
        }
    }
}

// ---------------------------------------------------------------------------
// GEMM2 (fallback): C[M,64] = A[M,256] @ B[256,64]
// ---------------------------------------------------------------------------
__global__ __launch_bounds__(256) void gemm2_f32(const float* __restrict__ A,
                                                 const float* __restrict__ B,
                                                 float* __restrict__ C, int M) {
    __shared__ float As[32][132];
    __shared__ float Bs[32][64];
    const int tid = threadIdx.x;
    const int m0 = blockIdx.y * 128;
    const int tr = (tid >> 3) << 2;
    const int tc = (tid & 7) << 3;

    float acc[4][8] = {{0.f}};

    for (int k0 = 0; k0 < 256; k0 += 32) {
#pragma unroll
        for (int i = 0; i < 4; i++) {
            const int f = tid + 256 * i;
            const int r = f >> 3;
            const int q = (f & 7) << 2;
            const int grow = m0 + r;
            float4 v = make_float4(0.f, 0.f, 0.f, 0.f);
            if (grow < M) v = *(const float4*)&A[(size_t)grow * 256 + k0 + q];
            As[q + 0][r] = v.x;
            As[q + 1][r] = v.y;
            As[q + 2][r] = v.z;
            As[q + 3][r] = v.w;
        }
#pragma unroll
        for (int i = 0; i < 2; i++) {
            const int f = tid + 256 * i;
            const int r = f >> 4;
            const int c4 = (f & 15) << 2;
            *(float4*)&Bs[r][c4] = *(const float4*)&B[(size_t)(k0 + r) * 64 + c4];
        }
        __syncthreads();
#pragma unroll
        for (int k = 0; k < 32; k++) {
            float av[4], bv[8];
            *(float4*)&av[0] = *(const float4*)&As[k][tr];
            *(float4*)&bv[0] = *(const float4*)&Bs[k][tc];
            *(float4*)&bv[4] = *(const float4*)&Bs[k][tc + 4];
#pragma unroll
            for (int r = 0; r < 4; r++)
#pragma unroll
                for (int c = 0; c < 8; c++)
                    acc[r][c] = fmaf(av[r], bv[c], acc[r][c]);
        }
        __syncthreads();
    }
#pragma unroll
    for (int r = 0; r < 4; r++) {
        const int grow = m0 + tr + r;
        if (grow < M) {
            *(float4*)&C[(size_t)grow * 64 + tc] =
                make_float4(acc[r][0], acc[r][1], acc[r][2], acc[r][3]);
            *(float4*)&C[(size_t)grow * 64 + tc + 4] =
                make_float4(acc[r][4], acc[r][5], acc[r][6], acc[r][7]);
        }
    }
}

// ===========================================================================
// Fused GEMM1+GEMM2 (batched) v4: D[M4,64] = relu(dinv*A@W1 + b1) @ W2.
// v1 structure (32-row tile, acc[4][8] fully retired into Ts before phase 2
// -> no spills) + two fixes: TS_LD=36 (16B-aligned, conflict-free b128 Ts
// reads) and 4x4 phase-2 micro-tile with 64-k W2 chunks (8 barriers vs 32).
// ===========================================================================
struct Gemm12B {
    const float* A;      // [M4,128]
    const float* W1;     // [128,256]
    const float* W2;     // [256,64]
    const float* b1;     // [256]
    const float* dinv;   // [8N] global; d_inv at g*2N + lr
    float* D;            // [M4,64]
    int Nn;
};

#define TS_LD 36

__global__ __launch_bounds__(256) void gemm12_b(Gemm12B a) {
    // LDS (floats):
    //  phase1: As[32][36] @ 0..1151, Bs[32][256] @ 1152..9343
    //  phase2: Ts[256][36] @ 0..9215, W2s[64][64] @ 9216..13311
    //  reduce: Rs[32][68] aliases Ts
    __shared__ float smem[13312];
    float* As  = smem;
    float* Bs  = smem + 1152;
    float* Ts  = smem;
    float* W2s = smem + 9216;
    float* Rs  = smem;

    const int M4 = 4 * a.Nn;
    const int tid = threadIdx.x;
    const int m0 = blockIdx.x * 32;
    const int rq = (tid >> 5) << 2;      // 0..28 (row quad)
    const int cq = (tid & 31) << 2;      // 0..124 (col quad; cols cq & cq+128)

    float acc[4][8] = {{0.f}};

    // ---------------- phase 1: T' = A @ W1 (32x256 per block) ----------------
    for (int k0 = 0; k0 < 128; k0 += 32) {
        {   // stage A chunk [32 rows][32 k] -> As[k][m]
            const int r = tid >> 3;
            const int q = (tid & 7) << 2;
            const int grow = m0 + r;
            float4 v = make_float4(0.f, 0.f, 0.f, 0.f);
            if (grow < M4) v = *(const float4*)&a.A[(size_t)grow * 128 + k0 + q];
            As[(q + 0) * 36 + r] = v.x;
            As[(q + 1) * 36 + r] = v.y;
            As[(q + 2) * 36 + r] = v.z;
            As[(q + 3) * 36 + r] = v.w;
        }
#pragma unroll
        for (int i = 0; i < 8; i++) {   // stage W1 chunk [32 k][256] -> Bs
            const int f = tid + 256 * i;
            const int r = f >> 6;
            const int c4 = (f & 63) << 2;
            *(float4*)&Bs[r * 256 + c4] = *(const float4*)&a.W1[(size_t)(k0 + r) * 256 + c4];
        }
        __syncthreads();
#pragma unroll
        for (int k = 0; k < 32; k++) {
            float av[4], bv[8];
            *(float4*)&av[0] = *(const float4*)&As[k * 36 + rq];
            *(float4*)&bv[0] = *(const float4*)&Bs[k * 256 + cq];
            *(float4*)&bv[4] = *(const float4*)&Bs[k * 256 + cq + 128];
#pragma unroll
            for (int r = 0; r < 4; r++)
#pragma unroll
                for (int c = 0; c < 8; c++)
                    acc[r][c] = fmaf(av[r], bv[c], acc[r][c]);
        }
        __syncthreads();
    }

    // epilogue-1: T = relu(acc*s + b1) -> Ts[k][m]; acc dies here (no spills).
    {
        float b1lo[4], b1hi[4], s[4];
#pragma unroll
        for (int j = 0; j < 4; j++) {
            b1lo[j] = a.b1[cq + j];
            b1hi[j] = a.b1[cq + 128 + j];
        }
#pragma unroll
        for (int r = 0; r < 4; r++) {
            const int gr = m0 + rq + r;
            float sv = 0.f;
            if (gr < M4) {
                const int g = gr / a.Nn;
                const int lr = gr - g * a.Nn;
                sv = a.dinv[(size_t)g * 2 * a.Nn + lr];
            }
            s[r] = sv;
        }
#pragma unroll
        for (int r = 0; r < 4; r++)
#pragma unroll
            for (int j = 0; j < 4; j++) {
                Ts[(cq + j) * TS_LD + rq + r] =
                    fmaxf(fmaf(acc[r][j], s[r], b1lo[j]), 0.f);
                Ts[(cq + 128 + j) * TS_LD + rq + r] =
                    fmaxf(fmaf(acc[r][4 + j], s[r], b1hi[j]), 0.f);
            }
    }

    // ---------------- phase 2: D[32,64] = T @ W2 ----------------
    const int col4 = (tid & 15) << 2;         // 16 col-groups x 4 = 64 cols
    const int row4 = ((tid >> 4) & 7) << 2;   // 8 row-groups x 4 = 32 rows
    const int kpar = tid >> 7;                // 0/1 (wave-pair aligned)

    float4 d[4];
#pragma unroll
    for (int r = 0; r < 4; r++) d[r] = make_float4(0.f, 0.f, 0.f, 0.f);

    for (int kc = 0; kc < 4; kc++) {          // 64-k W2 chunks
        __syncthreads();                      // Ts visible (kc=0) / prev W2s reads done
#pragma unroll
        for (int i = 0; i < 4; i++) {         // stage W2 [64 k][64]
            const int f = tid + 256 * i;
            const int kr = f >> 4;
            const int c4 = (f & 15) << 2;
            *(float4*)&W2s[kr * 64 + c4] =
                *(const float4*)&a.W2[(size_t)(kc * 64 + kr) * 64 + c4];
        }
        __syncthreads();
#pragma unroll
        for (int jj = 0; jj < 32; jj++) {
            const int k = (jj << 1) | kpar;   // 0..63 within chunk
            const float4 tv = *(const float4*)&Ts[(kc * 64 + k) * TS_LD + row4];
            const float4 wv = *(const float4*)&W2s[k * 64 + col4];
            d[0].x = fmaf(tv.x, wv.x, d[0].x); d[0].y = fmaf(tv.x, wv.y, d[0].y);
            d[0].z = fmaf(tv.x, wv.z, d[0].z); d[0].w = fmaf(tv.x, wv.w, d[0].w);
            d[1].x = fmaf(tv.y, wv.x, d[1].x); d[1].y = fmaf(tv.y, wv.y, d[1].y);
            d[1].z = fmaf(tv.y, wv.z, d[1].z); d[1].w = fmaf(tv.y, wv.w, d[1].w);
            d[2].x = fmaf(tv.z, wv.x, d[2].x); d[2].y = fmaf(tv.z, wv.y, d[2].y);
            d[2].z = fmaf(tv.z, wv.z, d[2].z); d[2].w = fmaf(tv.z, wv.w, d[2].w);
            d[3].x = fmaf(tv.w, wv.x, d[3].x); d[3].y = fmaf(tv.w, wv.y, d[3].y);
            d[3].z = fmaf(tv.w, wv.z, d[3].z); d[3].w = fmaf(tv.w, wv.w, d[3].w);
        }
    }

    // ---------------- reduce the 2 k-parity partials, store ----------------
    __syncthreads();                          // all Ts reads done -> Rs may alias
    if (kpar == 1) {
#pragma unroll
        for (int r = 0; r < 4; r++)
            *(float4*)&Rs[(row4 + r) * 68 + col4] = d[r];
    }
    __syncthreads();
    if (kpar == 0) {
#pragma unroll
        for (int r = 0; r < 4; r++) {
            const int grow = m0 + row4 + r;
            if (grow < M4) {
                const float4 p = *(const float4*)&Rs[(row4 + r) * 68 + col4];
                float4 o = make_float4(d[r].x + p.x, d[r].y + p.y,
                                       d[r].z + p.z, d[r].w + p.w);
                *(float4*)&a.D[(size_t)grow * 64 + col4] = o;
            }
        }
    }
}

// ---------------------------------------------------------------------------
// hyperedge embedding
// ---------------------------------------------------------------------------
__global__ __launch_bounds__(256) void hye_emb_kernel(const float* __restrict__ emb,
                                                      const int* __restrict__ hnode,
                                                      const float* __restrict__ hlen,
                                                      float* __restrict__ out, int Nn) {
    const int r = blockIdx.x * 16 + (threadIdx.x >> 4);
    const int c = (threadIdx.x & 15) << 2;
    if (r >= Nn) return;
    const int4* hp4 = (const int4*)&hnode[(size_t)r * 16];
    const int4 w0 = hp4[0], w1 = hp4[1], w2 = hp4[2], w3 = hp4[3];
    int idx[16] = {w0.x, w0.y, w0.z, w0.w, w1.x, w1.y, w1.z, w1.w,
                   w2.x, w2.y, w2.z, w2.w, w3.x, w3.y, w3.z, w3.w};
    float4 a0 = make_float4(0.f, 0.f, 0.f, 0.f);
    float4 a1 = make_float4(0.f, 0.f, 0.f, 0.f);
    float4 a2 = make_float4(0.f, 0.f, 0.f, 0.f);
    float4 a3 = make_float4(0.f, 0.f, 0.f, 0.f);
#pragma unroll
    for (int l = 0; l < 16; l += 4) {
        if (idx[l + 0] > 0) {
            const float4 v = *(const float4*)&emb[(size_t)(idx[l + 0] - 1) * 64 + c];
            a0.x += v.x; a0.y += v.y; a0.z += v.z; a0.w += v.w;
        }
        if (idx[l + 1] > 0) {
            const float4 v = *(const float4*)&emb[(size_t)(idx[l + 1] - 1) * 64 + c];
            a1.x += v.x; a1.y += v.y; a1.z += v.z; a1.w += v.w;
        }
        if (idx[l + 2] > 0) {
            const float4 v = *(const float4*)&emb[(size_t)(idx[l + 2] - 1) * 64 + c];
            a2.x += v.x; a2.y += v.y; a2.z += v.z; a2.w += v.w;
        }
        if (idx[l + 3] > 0) {
            const float4 v = *(const float4*)&emb[(size_t)(idx[l + 3] - 1) * 64 + c];
            a3.x += v.x; a3.y += v.y; a3.z += v.z; a3.w += v.w;
        }
    }
    const float inv = 1.0f / (hlen[r] + 1e-15f);
    float4 acc;
    acc.x = (a0.x + a1.x + a2.x + a3.x) * inv;
    acc.y = (a0.y + a1.y + a2.y + a3.y) * inv;
    acc.z = (a0.z + a1.z + a2.z + a3.z) * inv;
    acc.w = (a0.w + a1.w + a2.w + a3.w) * inv;
    *(float4*)&out[(size_t)r * 64 + c] = acc;
}

struct HyeB {
    const float* emb;      // contiguous h2 [4Nn,64]
    const int* hnode[4];
    const float* hlen[4];
    float* out;            // contiguous hemb [4Nn,64]
    int Nn;
};

__global__ __launch_bounds__(256) void hye_b(HyeB a) {
    const int gr = blockIdx.x * 16 + (threadIdx.x >> 4);
    const int c = (threadIdx.x & 15) << 2;
    if (gr >= 4 * a.Nn) return;
    const int g = gr / a.Nn;
    const int lr = gr - g * a.Nn;
    const float* __restrict__ emb = a.emb + (size_t)g * a.Nn * 64;
    const int4* hp4 = (const int4*)&a.hnode[g][(size_t)lr * 16];
    const int4 w0 = hp4[0], w1 = hp4[1], w2 = hp4[2], w3 = hp4[3];
    int idx[16] = {w0.x, w0.y, w0.z, w0.w, w1.x, w1.y, w1.z, w1.w,
                   w2.x, w2.y, w2.z, w2.w, w3.x, w3.y, w3.z, w3.w};
    float4 a0 = make_float4(0.f, 0.f, 0.f, 0.f);
    float4 a1 = make_float4(0.f, 0.f, 0.f, 0.f);
    float4 a2 = make_float4(0.f, 0.f, 0.f, 0.f);
    float4 a3 = make_float4(0.f, 0.f, 0.f, 0.f);
#pragma unroll
    for (int l = 0; l < 16; l += 4) {
        if (idx[l + 0] > 0) {
            const float4 v = *(const float4*)&emb[(size_t)(idx[l + 0] - 1) * 64 + c];
            a0.x += v.x; a0.y += v.y; a0.z += v.z; a0.w += v.w;
        }
        if (idx[l + 1] > 0) {
            const float4 v = *(const float4*)&emb[(size_t)(idx[l + 1] - 1) * 64 + c];
            a1.x += v.x; a1.y += v.y; a1.z += v.z; a1.w += v.w;
        }
        if (idx[l + 2] > 0) {
            const float4 v = *(const float4*)&emb[(size_t)(idx[l + 2] - 1) * 64 + c];
            a2.x += v.x; a2.y += v.y; a2.z += v.z; a2.w += v.w;
        }
        if (idx[l + 3] > 0) {
            const float4 v = *(const float4*)&emb[(size_t)(idx[l + 3] - 1) * 64 + c];
            a3.x += v.x; a3.y += v.y; a3.z += v.z; a3.w += v.w;
        }
    }
    const float inv = 1.0f / (a.hlen[g][lr] + 1e-15f);
    float4 acc;
    acc.x = (a0.x + a1.x + a2.x + a3.x) * inv;
    acc.y = (a0.y + a1.y + a2.y + a3.y) * inv;
    acc.z = (a0.z + a1.z + a2.z + a3.z) * inv;
    acc.w = (a0.w + a1.w + a2.w + a3.w) * inv;
    *(float4*)&a.out[(size_t)gr * 64 + c] = acc;
}

// ---------------------------------------------------------------------------
// Fusion-attention scores
// ---------------------------------------------------------------------------
struct AttnArgs {
    const float* z[8];
    const float* W1c; const float* b1c; const float* W2c;
    const float* W1m; const float* b1m; const float* W2m;
    float* accw;
    int Nn;
};

__global__ __launch_bounds__(256) void attn_gemm(AttnArgs a) {
    __shared__ float As[64][68];    // [k][m], 64 rows
    __shared__ float Bs[64][128];   // [k][h]
    __shared__ float red[4];
    const int tid = threadIdx.x;
    const int gy = blockIdx.y;
    const int head = gy >> 2;
    const float* __restrict__ z  = a.z[gy];
    const float* __restrict__ W1 = head ? a.W1m : a.W1c;
    const float* __restrict__ b1 = head ? a.b1m : a.b1c;
    const float* __restrict__ W2 = head ? a.W2m : a.W2c;
    const int m0 = blockIdx.x * 64;

    {
        const int m = tid >> 2;
        const int qb = tid & 3;
        const int grow = m0 + m;
#pragma unroll
        for (int it = 0; it < 4; it++) {
            const int q = qb + 4 * it;
            float4 v = make_float4(0.f, 0.f, 0.f, 0.f);
            if (grow < a.Nn) v = *(const float4*)&z[(size_t)grow * 64 + q * 4];
            As[q * 4 + 0][m] = v.x;
            As[q * 4 + 1][m] = v.y;
            As[q * 4 + 2][m] = v.z;
            As[q * 4 + 3][m] = v.w;
        }
    }
    {
#pragma unroll
        for (int i = 0; i < 8; i++) {
            const int f = tid + 256 * i;
            const int r = f >> 5, cc = (f & 31) << 2;
            *(float4*)&Bs[r][cc] = *(const float4*)&W1[(size_t)r * 128 + cc];
        }
    }
    __syncthreads();

    const int mq = (tid & 15) << 2;
    const int cq = (tid >> 4) << 2;
    float acc[4][8] = {{0.f}};
    for (int k = 0; k < 64; k++) {
        float av[4], bv[8];
        *(float4*)&av[0] = *(const float4*)&As[k][mq];
        *(float4*)&bv[0] = *(const float4*)&Bs[k][cq];
        *(float4*)&bv[4] = *(const float4*)&Bs[k][cq + 64];
#pragma unroll
        for (int r = 0; r < 4; r++)
#pragma unroll
            for (int c = 0; c < 8; c++)
                acc[r][c] = fmaf(av[r], bv[c], acc[r][c]);
    }

    float w2v[8], b1v[8];
#pragma unroll
    for (int c = 0; c < 8; c++) {
        const int col = cq + (c & 3) + ((c >> 2) << 6);
        w2v[c] = W2[col];
        b1v[c] = b1[col];
    }
    float local = 0.f;
#pragma unroll
    for (int r = 0; r < 4; r++) {
        if (m0 + mq + r < a.Nn) {
#pragma unroll
            for (int c = 0; c < 8; c++) {
                float s = acc[r][c] + b1v[c];
                s = fminf(fmaxf(s, -15.f), 15.f);
                const float t = __expf(2.f * s);
                local += (1.f - 2.f / (t + 1.f)) * w2v[c];
            }
        }
    }
#pragma unroll
    for (int off = 32; off >= 1; off >>= 1) local += __shfl_down(local, off, 64);
    if ((tid & 63) == 0) red[tid >> 6] = local;
    __syncthreads();
    if (tid == 0) atomicAdd(&a.accw[gy], red[0] + red[1] + red[2] + red[3]);
}

__global__ void softmax_beta(const float* __restrict__ acc, float* __restrict__ beta,
                             float invN) {
    const int t = threadIdx.x;
    if (t < 2) {
        const float* a = acc + 4 * t;
        float* b = beta + 4 * t;
        float w[4], m = -1e30f;
#pragma unroll
        for (int i = 0; i < 4; i++) { w[i] = a[i] * invN; m = fmaxf(m, w[i]); }
        float s = 0.f;
#pragma unroll
        for (int i = 0; i < 4; i++) { w[i] = expf(w[i] - m); s += w[i]; }
#pragma unroll
        for (int i = 0; i < 4; i++) b[i] = w[i] / s;
    }
}

__global__ __launch_bounds__(256) void weighted_sum(const float* __restrict__ z0,
                                                    const float* __restrict__ z1,
                                                    const float* __restrict__ z2,
                                                    const float* __restrict__ z3,
                                                    const float* __restrict__ beta,
                                                    float* __restrict__ out, int Nn) {
    const int t = blockIdx.x * 256 + threadIdx.x;
    if (t >= Nn * 16) return;
    const float b0 = beta[0], b1 = beta[1], b2 = beta[2], b3 = beta[3];
    const float4 v0 = *(const float4*)&z0[(size_t)t * 4];
    const float4 v1 = *(const float4*)&z1[(size_t)t * 4];
    const float4 v2 = *(const float4*)&z2[(size_t)t * 4];
    const float4 v3 = *(const float4*)&z3[(size_t)t * 4];
    float4 o;
    o.x = b0 * v0.x + b1 * v1.x + b2 * v2.x + b3 * v3.x;
    o.y = b0 * v0.y + b1 * v1.y + b2 * v2.y + b3 * v3.y;
    o.z = b0 * v0.z + b1 * v1.z + b2 * v2.z + b3 * v3.z;
    o.w = b0 * v0.w + b1 * v1.w + b2 * v2.w + b3 * v3.w;
    *(float4*)&out[(size_t)t * 4] = o;
}

// ---------------------------------------------------------------------------
extern "C" void kernel_launch(void* const* d_in, const int* in_sizes, int n_in,
                              void* d_out, int out_size, void* d_ws, size_t ws_size,
                              hipStream_t stream) {
    const int Nn = in_sizes[0] / NF;   // 50000
    const int E  = in_sizes[1] / 2;    // 800000
    const int N2 = 2 * Nn;

    const float* x[4];
    const int*   ei[4];
    const int*   hnode[4];
    const float* hlen[4];
    for (int g = 0; g < 4; g++) {
        x[g]     = (const float*)d_in[4 * g + 0];
        ei[g]    = (const int*)d_in[4 * g + 1];
        hnode[g] = (const int*)d_in[4 * g + 2];
        hlen[g]  = (const float*)d_in[4 * g + 3];
    }
    const float* W1   = (const float*)d_in[16];
    const float* b1   = (const float*)d_in[17];
    const float* W2   = (const float*)d_in[18];
    const float* b2   = (const float*)d_in[19];
    const float* acW1 = (const float*)d_in[20];
    const float* acb1 = (const float*)d_in[21];
    const float* acW2 = (const float*)d_in[22];
    const float* amW1 = (const float*)d_in[23];
    const float* amb1 = (const float*)d_in[24];
    const float* amW2 = (const float*)d_in[25];

    // ---- batched-path workspace requirement (~183 MB < fallback's ~216 MB) ----
    const size_t fRA   = (size_t)4 * Nn * 64;    // ping: gather128 half-out; later D; later hemb
    const size_t fRB   = (size_t)4 * Nn * 128;   // B2 [4N,128]; later h2 (lo) + E1 (hi)
    const size_t fDinv = (size_t)4 * N2;
    const size_t fcnt  = fRA + fRB + fDinv + 16;
    const size_t icnt  = ((size_t)4 * N2 + 4) + 512 + (size_t)8 * E;
    const size_t need  = (fcnt + icnt) * sizeof(float) + 256;
    const bool raFitsInts = fRA * sizeof(float) >=
                            ((size_t)4 * N2 + (size_t)4 * E) * sizeof(int);

    if (need <= ws_size && raFitsInts) {
        // =================== batched path ===================
        float* ws = (float*)d_ws;
        size_t o = 0;
        float* RA   = ws + o; o += fRA;   // [2N,128] ping == [4N,64]
        float* RB   = ws + o; o += fRB;   // [4N,128]
        float* dinv = ws + o; o += fDinv;
        float* accw = ws + o; o += 8;
        float* beta = ws + o; o += 8;
        int* iws = (int*)(ws + o);
        size_t io = 0;
        int* off      = iws + io; io += (size_t)4 * N2 + 4;
        int* partials = iws + io; io += 512;
        int* srcidx   = iws + io; io += (size_t)8 * E;
        // transient build ints aliased into RA (dead before RA's first write)
        int* deg  = (int*)RA;
        int* rank = deg + (size_t)4 * N2;

        const int n8 = 4 * N2;                     // 400000
        const int nScanBlocks = cdiv(n8, 1024);    // 391 <= 512

        BuildB bb;
        for (int g = 0; g < 4; g++) { bb.nidx[g] = ei[g]; bb.eidx[g] = ei[g] + E; }
        bb.deg = deg; bb.rank = rank; bb.off = off; bb.srcidx = srcidx;
        bb.Nn = Nn; bb.E = E; bb.shardSize = cdiv(Nn, 8);

        hipMemsetAsync(deg, 0, (size_t)n8 * sizeof(int), stream);
        count_rank_b<<<dim3(cdiv(E, 256), 4), 256, 0, stream>>>(bb);
        scan_blocks<<<nScanBlocks, 256, 0, stream>>>(deg, off, partials, n8);
        scan_partials<<<1, 512, 0, stream>>>(partials, nScanBlocks);
        scan_add<<<cdiv(n8, 256), 256, 0, stream>>>(off, partials, n8, 2 * 4 * E);
        build_fill_b<<<dim3(8 * cdiv(E, 1024), 4), 256, 0, stream>>>(bb);
        invert_deg_int<<<cdiv(n8, 256), 256, 0, stream>>>(deg, dinv, n8);
        // RA's int aliases (deg/rank) are now dead.

        // ---- hconv1 gathers, two 2-graph halves through RA ----
        const int gh = cdiv(2 * Nn, 16);
        for (int h = 0; h < 2; h++) {
            const int gb = 2 * h;
            Gather128H p1;
            p1.src[0] = x[gb]; p1.src[1] = x[gb + 1];
            p1.dst = RA; p1.off = off; p1.srcidx = srcidx;
            p1.dinv = dinv; p1.gbase = gb; p1.passBase = Nn; p1.Nn = Nn;  // edge, b_inv
            gather128_h<<<gh, 256, 0, stream>>>(p1);

            Gather128H p2;
            p2.src[0] = RA; p2.src[1] = RA + (size_t)Nn * 128;
            p2.dst = RB + (size_t)gb * Nn * 128;
            p2.off = off; p2.srcidx = srcidx;
            p2.dinv = nullptr; p2.gbase = gb; p2.passBase = 0; p2.Nn = Nn; // node
            gather128_h<<<gh, 256, 0, stream>>>(p2);
        }

        // ---- fused hconv1-GEMM + hconv2-GEMM: RB -> D (in RA) ----
        float* Dbuf = RA;   // [4N,64], RA fully dead-written
        Gemm12B gm;
        gm.A = RB; gm.W1 = W1; gm.W2 = W2; gm.b1 = b1;
        gm.dinv = dinv; gm.D = Dbuf; gm.Nn = Nn;
        gemm12_b<<<cdiv(4 * Nn, 32), 256, 0, stream>>>(gm);

        // ---- hconv2 gathers ----
        float* E1  = RB + (size_t)4 * Nn * 64;   // RB upper half [4N,64]
        float* h2b = RB;                          // RB lower half [4N,64]
        Gather64B g3;
        for (int g = 0; g < 4; g++) g3.src[g] = Dbuf + (size_t)g * Nn * 64;
        g3.dst = E1; g3.off = off; g3.srcidx = srcidx;
        g3.dinv = dinv; g3.post_bias = nullptr; g3.passBase = Nn; g3.Nn = Nn;
        gather64_b<<<cdiv(4 * Nn, 32), 256, 0, stream>>>(g3);

        Gather64B g4;
        for (int g = 0; g < 4; g++) g4.src[g] = E1 + (size_t)g * Nn * 64;
        g4.dst = h2b; g4.off = off; g4.srcidx = srcidx;
        g4.dinv = dinv; g4.post_bias = b2; g4.passBase = 0; g4.Nn = Nn;
        gather64_b<<<cdiv(4 * Nn, 32), 256, 0, stream>>>(g4);

        // ---- hyperedge embedding: h2b (RB lo) -> hemb (RA, D dead) ----
        float* hembb = RA;
        HyeB hb;
        hb.emb = h2b;
        for (int g = 0; g < 4; g++) { hb.hnode[g] = hnode[g]; hb.hlen[g] = hlen[g]; }
        hb.out = hembb; hb.Nn = Nn;
        hye_b<<<cdiv(4 * Nn, 16), 256, 0, stream>>>(hb);

        // ---- fusion attention ----
        const size_t st = (size_t)Nn * 64;
        hipMemsetAsync(accw, 0, 8 * sizeof(float), stream);
        AttnArgs aa;
        aa.z[0] = h2b + 1 * st; aa.z[1] = hembb + 0 * st;
        aa.z[2] = h2b + 2 * st; aa.z[3] = hembb + 2 * st;
        aa.z[4] = h2b + 0 * st; aa.z[5] = hembb + 1 * st;
        aa.z[6] = h2b + 3 * st; aa.z[7] = hembb + 3 * st;
        aa.W1c = acW1; aa.b1c = acb1; aa.W2c = acW2;
        aa.W1m = amW1; aa.b1m = amb1; aa.W2m = amW2;
        aa.accw = accw; aa.Nn = Nn;
        attn_gemm<<<dim3(cdiv(Nn, 64), 8), 256, 0, stream>>>(aa);
        softmax_beta<<<1, 64, 0, stream>>>(accw, beta, 1.0f / (float)Nn);

        float* out = (float*)d_out;
        weighted_sum<<<cdiv(Nn * 16, 256), 256, 0, stream>>>(
            aa.z[0], aa.z[1], aa.z[2], aa.z[3], beta + 0, out, Nn);
        weighted_sum<<<cdiv(Nn * 16, 256), 256, 0, stream>>>(
            aa.z[4], aa.z[5], aa.z[6], aa.z[7], beta + 4, out + (size_t)Nn * DD2, Nn);
        return;
    }

    // =================== fallback: proven per-graph path ===================
    float* ws = (float*)d_ws;
    size_t o = 0;
    float* bufA = ws + o; o += (size_t)Nn * DD1;
    float* bufB = ws + o; o += (size_t)Nn * DD1;
    float* dinv = ws + o; o += N2;
    float* h2[4];
    float* hemb[4];
    for (int g = 0; g < 4; g++) { h2[g]   = ws + o; o += (size_t)Nn * DD2; }
    for (int g = 0; g < 4; g++) { hemb[g] = ws + o; o += (size_t)Nn * DD2; }
    float* accw = ws + o; o += 8;
    float* beta = ws + o; o += 8;
    int* iws = (int*)(ws + o);
    size_t io = 0;
    int* deg_i    = iws + io; io += N2;
    int* off      = iws + io; io += N2 + 1;
    int* partials = iws + io; io += 512;
    int* rank     = iws + io; io += E;
    int* srcidx   = iws + io; io += (size_t)2 * E;

    const int nScanBlocks = cdiv(N2, 1024);
    const int shardSize = cdiv(Nn, 8);

    for (int g = 0; g < 4; g++) {
        const int* nidx = ei[g];
        const int* eidx = ei[g] + E;
        const int* off_n = off;
        const int* off_e = off + Nn;
        const float* d_inv = dinv;
        const float* b_inv = dinv + Nn;

        hipMemsetAsync(deg_i, 0, (size_t)N2 * sizeof(int), stream);
        count_rank<<<cdiv(E, 256), 256, 0, stream>>>(nidx, eidx, deg_i, rank, Nn, E);
        scan_blocks<<<nScanBlocks, 256, 0, stream>>>(deg_i, off, partials, N2);
        scan_partials<<<1, 512, 0, stream>>>(partials, nScanBlocks);
        scan_add<<<cdiv(N2, 256), 256, 0, stream>>>(off, partials, N2, 2 * E);
        build_fill<<<8 * cdiv(E, 1024), 256, 0, stream>>>(nidx, eidx, rank, off,
                                                          srcidx, Nn, E, shardSize);
        invert_deg_int<<<cdiv(N2, 256), 256, 0, stream>>>(deg_i, dinv, N2);

        gather_rows_128<<<cdiv(Nn, 16), 256, 0, stream>>>(x[g], off_e, srcidx, b_inv, bufB, Nn);
        gather_rows_128<<<cdiv(Nn, 16), 256, 0, stream>>>(bufB, off_n, srcidx, nullptr, bufA, Nn);
        gemm1_f32<<<dim3(2, cdiv(Nn, 128)), 256, 0, stream>>>(bufA, W1, bufB, Nn, d_inv, b1);

        gemm2_f32<<<dim3(1, cdiv(Nn, 128)), 256, 0, stream>>>(bufB, W2, bufA, Nn);
        gather_rows_64<<<cdiv(Nn, 32), 256, 0, stream>>>(bufA, off_e, srcidx, b_inv,
                                                         nullptr, bufB, Nn);
        gather_rows_64<<<cdiv(Nn, 32), 256, 0, stream>>>(bufB, off_n, srcidx, d_inv,
                                                         b2, h2[g], Nn);

        hye_emb_kernel<<<cdiv(Nn, 16), 256, 0, stream>>>(h2[g], hnode[g], hlen[g], hemb[g], Nn);
    }

    hipMemsetAsync(accw, 0, 8 * sizeof(float), stream);
    AttnArgs aa;
    aa.z[0] = h2[1]; aa.z[1] = hemb[0]; aa.z[2] = h2[2]; aa.z[3] = hemb[2];
    aa.z[4] = h2[0]; aa.z[5] = hemb[1]; aa.z[6] = h2[3]; aa.z[7] = hemb[3];
    aa.W1c = acW1; aa.b1c = acb1; aa.W2c = acW2;
    aa.W1m = amW1; aa.b1m = amb1; aa.W2m = amW2;
    aa.accw = accw; aa.Nn = Nn;
    attn_gemm<<<dim3(cdiv(Nn, 64), 8), 256, 0, stream>>>(aa);
    softmax_beta<<<1, 64, 0, stream>>>(accw, beta, 1.0f / (float)Nn);

    float* out = (float*)d_out;
    weighted_sum<<<cdiv(Nn * 16, 256), 256, 0, stream>>>(h2[1], hemb[0], h2[2], hemb[2],
                                                         beta + 0, out, Nn);
    weighted_sum<<<cdiv(Nn * 16, 256), 256, 0, stream>>>(h2[0], hemb[1], h2[3], hemb[3],
                                                         beta + 4, out + (size_t)Nn * DD2, Nn);
}